// Round 15
// baseline (283.277 us; speedup 1.0000x reference)
//
#include <hip/hip_runtime.h>

// ---------------------------------------------------------------------------
// LinearSSM: x_{t+1} = x_t @ A + u_t @ B   (batch=64, T=1024, n=512, p=128)
// Fully parallel chunked solve.  All heavy GEMMs: proven 2-barrier structure,
// global_load_lds 16B into XOR-swizzled LDS, __launch_bounds__(256,5)
// (VGPR 64, LDS <= 32KB -> 5 blocks/CU).
//   prep: bf16 casts of A only (2048 blocks)
//   pow stages (grid 256 each): A^2..A^64 dual chains; wk rides stage 3;
//     B/x0/identity ride stage 0; u-pack rides stages 1,3,4,5
//   e1g: E1[c] = u-chunk . Wstack -> E1slab   (512 blocks, 64x128, K=1024)
//   e2g: E2[g] = sum_t E1[8g+t].A^{8(7-t)}    (512 blocks, 32x32, K=4096)
//   s1x: S1[c'] c'=0..128 -> Z state cols (c'<=127) AND dout[t=8c'-1]
//   outg: out = Z[:, :K_k] . [At[k+1] | Wt..]^T for k=0..6
// ---------------------------------------------------------------------------

typedef __attribute__((ext_vector_type(8))) short bf16x8;
typedef __attribute__((ext_vector_type(8))) unsigned short ushort8;
typedef __attribute__((ext_vector_type(4))) float f32x4;
typedef unsigned short ushort_t;

#define MFMA16(a, b, c) __builtin_amdgcn_mfma_f32_16x16x32_bf16(a, b, c, 0, 0, 0)

// workspace layout (bytes)
#define OFF_AT  0UL           // 17 slots (A^p)^T bf16 [512][512]; slot16 = I
#define OFF_AU  8912896UL     // 12 slots A^p bf16 [512][512]
#define OFF_BT  15204352UL    // B^T bf16 [512][128]
#define OFF_BU  15335424UL    // B   bf16 [128][512]
#define OFF_WT  15466496UL    // 8 x (B.A^p)^T bf16 [512][128]
#define OFF_Z   16515072UL    // [8192][1536] bf16: [S1 | u-chunk]
#define OFF_E1S 41680896UL    // [128][64][512] bf16 : E1 slab
#define OFF_E2S 50069504UL    // [17][64][512] bf16  : slot0 = x0, 1+g = E2[g]

__host__ __device__ __forceinline__ int slot_of(int p) {
    if (p == 0) return 16;          // identity
    if (p <= 8) return p - 1;
    return 7 + (p >> 3);            // 16,24,..,64 -> 9..15
}

__device__ __forceinline__ unsigned short f2bf(float f) {
    union { float f; unsigned u; } v; v.f = f;
    unsigned r = v.u + 0x7FFFu + ((v.u >> 16) & 1u);
    return (unsigned short)(r >> 16);
}

__device__ __forceinline__ int sel4(int4 v, int p) {
    return p == 0 ? v.x : p == 1 ? v.y : p == 2 ? v.z : v.w;
}

typedef __attribute__((address_space(3))) unsigned int as3_u32;
typedef __attribute__((address_space(1))) const unsigned int as1_u32;
__device__ __forceinline__ void gll16(const void* g, void* l) {
    __builtin_amdgcn_global_load_lds((as1_u32*)g, (as3_u32*)l, 16, 0, 0);
}

// ---------------------------------------------------------------------------
// prep: bf16 casts of A only.  524288 items, grid 2048.
// ---------------------------------------------------------------------------
__global__ __launch_bounds__(256) void prep_kernel(const float* __restrict__ A,
                                                   char* __restrict__ ws) {
    ushort_t* At1 = (ushort_t*)(ws + OFF_AT);
    ushort_t* Au1 = (ushort_t*)(ws + OFF_AU);
    long idx = (long)blockIdx.x * 256 + threadIdx.x;
    if (idx < 262144) {
        Au1[idx] = f2bf(A[idx]);                          // coalesced r/w
    } else {
        long gi = idx - 262144;
        int n = (int)(gi >> 9), k = (int)(gi & 511);
        At1[gi] = f2bf(A[(long)k * 512 + n]);             // scattered read, coal. write
    }
}

// ---------------------------------------------------------------------------
// pow tile body: At[d] = At[m] .NT Au[i] (prod 0); Au[d] = Au[i] .NT At[m] (1)
// ---------------------------------------------------------------------------
__device__ __forceinline__ void pow_tile(char* __restrict__ ws, ushort_t* ldsX,
                                         int d, int m_, int i_, int prod,
                                         int mb, int nb) {
    ushort_t* At = (ushort_t*)(ws + OFF_AT);
    ushort_t* Au = (ushort_t*)(ws + OFF_AU);
    const ushort_t *Xp, *Yp; ushort_t* outp;
    if (prod == 0) { Xp = At + (long)slot_of(m_) * 262144; Yp = Au + (long)slot_of(i_) * 262144; outp = At + (long)slot_of(d) * 262144; }
    else           { Xp = Au + (long)slot_of(i_) * 262144; Yp = At + (long)slot_of(m_) * 262144; outp = Au + (long)slot_of(d) * 262144; }

    int tid = threadIdx.x, w = tid >> 6, lane = tid & 63, q = lane >> 4, r = lane & 15;

    for (int i2 = tid; i2 < 64 * 64; i2 += 256) {
        int row = i2 >> 6, c8 = i2 & 63;
        ushort8 v = *(const ushort8*)(Xp + (long)(mb * 64 + row) * 512 + c8 * 8);
        *(ushort8*)&ldsX[row * 512 + ((c8 ^ (row & 7)) << 3)] = v;
    }
    __syncthreads();

    f32x4 acc[4][2];
    for (int a1 = 0; a1 < 4; a1++) for (int b1 = 0; b1 < 2; b1++) acc[a1][b1] = (f32x4){0.f, 0.f, 0.f, 0.f};

    int n0 = nb * 128 + w * 32;
    for (int kt = 0; kt < 16; kt++) {
        bf16x8 b0 = *(const bf16x8*)(Yp + (long)(n0 + r) * 512 + kt * 32 + q * 8);
        bf16x8 b1 = *(const bf16x8*)(Yp + (long)(n0 + 16 + r) * 512 + kt * 32 + q * 8);
        int g2 = kt * 4 + q;
#pragma unroll
        for (int mi = 0; mi < 4; mi++) {
            int row = mi * 16 + r;
            bf16x8 a = *(bf16x8*)&ldsX[row * 512 + ((g2 ^ (row & 7)) << 3)];
            acc[mi][0] = MFMA16(a, b0, acc[mi][0]);
            acc[mi][1] = MFMA16(a, b1, acc[mi][1]);
        }
    }
    for (int mi = 0; mi < 4; mi++) for (int nj = 0; nj < 2; nj++) {
        int m = mb * 64 + mi * 16 + q * 4, n = n0 + nj * 16 + r;
        for (int v = 0; v < 4; v++) outp[(long)(m + v) * 512 + n] = f2bf(acc[mi][nj][v]);
    }
}

// ---------------------------------------------------------------------------
// wk tile body: Wt[p] = (B.A^p)^T, p = 7-k8;  k8==7 -> copy B^T into Wt[0].
// ---------------------------------------------------------------------------
__device__ __forceinline__ void wk_tile(char* __restrict__ ws, ushort_t* ldsX,
                                        int k8, int mb) {
    ushort_t* At = (ushort_t*)(ws + OFF_AT);
    ushort_t* Bu = (ushort_t*)(ws + OFF_BU);
    ushort_t* Bt = (ushort_t*)(ws + OFF_BT);
    ushort_t* Wt = (ushort_t*)(ws + OFF_WT);

    int tid = threadIdx.x, w = tid >> 6, lane = tid & 63, q = lane >> 4, r = lane & 15;

    if (k8 == 7) {  // p = 0: Wt[0] = B^T
        for (int i2 = tid; i2 < 64 * 32; i2 += 256) {
            int row = i2 >> 5, c4 = i2 & 31;
            ushort4 v = *(const ushort4*)(Bt + (long)(mb * 64 + row) * 128 + c4 * 4);
            *(ushort4*)(Wt + (long)(mb * 64 + row) * 128 + c4 * 4) = v;
        }
        return;
    }

    int p = 7 - k8;
    const ushort_t* Xp = At + (long)slot_of(p) * 262144;
    for (int i2 = tid; i2 < 64 * 64; i2 += 256) {
        int row = i2 >> 6, c8 = i2 & 63;
        ushort8 v = *(const ushort8*)(Xp + (long)(mb * 64 + row) * 512 + c8 * 8);
        *(ushort8*)&ldsX[row * 512 + ((c8 ^ (row & 7)) << 3)] = v;
    }
    __syncthreads();

    f32x4 acc[4][2];
    for (int a1 = 0; a1 < 4; a1++) for (int b1 = 0; b1 < 2; b1++) acc[a1][b1] = (f32x4){0.f, 0.f, 0.f, 0.f};

    int n0 = w * 32;
    for (int kt = 0; kt < 16; kt++) {
        bf16x8 b0 = *(const bf16x8*)(Bu + (long)(n0 + r) * 512 + kt * 32 + q * 8);
        bf16x8 b1 = *(const bf16x8*)(Bu + (long)(n0 + 16 + r) * 512 + kt * 32 + q * 8);
        int g2 = kt * 4 + q;
#pragma unroll
        for (int mi = 0; mi < 4; mi++) {
            int row = mi * 16 + r;
            bf16x8 a = *(bf16x8*)&ldsX[row * 512 + ((g2 ^ (row & 7)) << 3)];
            acc[mi][0] = MFMA16(a, b0, acc[mi][0]);
            acc[mi][1] = MFMA16(a, b1, acc[mi][1]);
        }
    }
    ushort_t* Wp = Wt + (long)p * 65536;
    for (int mi = 0; mi < 4; mi++) for (int nj = 0; nj < 2; nj++) {
        int m = mb * 64 + mi * 16 + q * 4, n = n0 + nj * 16 + r;
        for (int v = 0; v < 4; v++) Wp[(long)(m + v) * 128 + n] = f2bf(acc[mi][nj][v]);
    }
}

// ---------------------------------------------------------------------------
// pow_stage: block-partitioned launch (grid 256):
//   [0, wkbase): pow tiles   [wkbase, ubase): wk tiles
//   [ubase, 256): riders -- umode 0: u-pack [ustart,uend); umode 1: B/x0/ident
// ---------------------------------------------------------------------------
__global__ __launch_bounds__(256) void pow_stage(char* __restrict__ ws,
                                                 const float* __restrict__ us,
                                                 const float* __restrict__ x0,
                                                 const float* __restrict__ B,
                                                 int4 dd, int4 mm, int4 ii,
                                                 int dual, int wkbase,
                                                 int ubase, int umode,
                                                 int ustart, int uend) {
    __shared__ ushort_t ldsX[64 * 512];
    int bx = blockIdx.x;

    if (ubase > 0 && bx >= ubase) {
        int tid = threadIdx.x;
        int nthr = (256 - ubase) * 256;
        if (umode == 0) {
            ushort_t* Z = (ushort_t*)(ws + OFF_Z);
            for (long gi = ustart + (long)(bx - ubase) * 256 + tid; gi < uend; gi += nthr) {
                int row = (int)(gi >> 7), g8 = (int)(gi & 127);
                int c = row >> 6, b = row & 63;
                const float* src = us + (long)b * 131072 + c * 1024 + g8 * 8;
                float4 v0 = *(const float4*)src;
                float4 v1 = *(const float4*)(src + 4);
                ushort8 h = { f2bf(v0.x), f2bf(v0.y), f2bf(v0.z), f2bf(v0.w),
                              f2bf(v1.x), f2bf(v1.y), f2bf(v1.z), f2bf(v1.w) };
                *(ushort8*)(Z + (long)row * 1536 + 512 + g8 * 8) = h;
            }
        } else {
            ushort_t* Bt  = (ushort_t*)(ws + OFF_BT);
            ushort_t* Bu  = (ushort_t*)(ws + OFF_BU);
            ushort_t* X0b = (ushort_t*)(ws + OFF_E2S);
            ushort_t* At1 = (ushort_t*)(ws + OFF_AT);
            for (long i = (long)(bx - ubase) * 256 + tid; i < 331776; i += nthr) {
                if (i < 65536) {
                    int kp = (int)(i >> 9), n = (int)(i & 511);
                    ushort_t v = f2bf(B[i]);
                    Bt[(long)n * 128 + kp] = v;
                    Bu[i] = v;
                } else if (i < 69632) {
                    long gi = i - 65536;
                    long e0 = gi * 8;
                    float4 v0 = *(const float4*)(x0 + e0);
                    float4 v1 = *(const float4*)(x0 + e0 + 4);
                    ushort8 h = { f2bf(v0.x), f2bf(v0.y), f2bf(v0.z), f2bf(v0.w),
                                  f2bf(v1.x), f2bf(v1.y), f2bf(v1.z), f2bf(v1.w) };
                    *(ushort8*)(X0b + e0) = h;
                } else {
                    long gi2 = i - 69632;
                    int n = (int)(gi2 >> 9), k2 = (int)(gi2 & 511);
                    At1[(long)16 * 262144 + gi2] = (n == k2) ? (ushort_t)0x3F80 : (ushort_t)0;
                }
            }
        }
        return;
    }
    if (wkbase > 0 && bx >= wkbase) {
        int widx = bx - wkbase;
        wk_tile(ws, ldsX, widx >> 3, widx & 7);
        return;
    }

    int nb = bx & 3, mb = (bx >> 2) & 7;
    int prod, pair;
    if (dual) { prod = (bx >> 5) & 1; pair = bx >> 6; }
    else      { prod = 0;             pair = bx >> 5; }
    int d = sel4(dd, pair), m_ = sel4(mm, pair), i_ = sel4(ii, pair);
    pow_tile(ws, ldsX, d, m_, i_, prod, mb, nb);
}

// ---------------------------------------------------------------------------
// e1g: E1[c] = Zu-chunk [64 x 1024] .NT Wstack -> E1slab[c]
// grid 512: c = bx>>2, nt = bx&3.  64m x 128n, 16 K-steps, stage-both.
// ---------------------------------------------------------------------------
__global__ __launch_bounds__(256, 5) void e1g(char* __restrict__ ws) {
    __shared__ ushort_t Alds[64 * 64];
    __shared__ ushort_t Blds[128 * 64];
    const ushort_t* Z  = (const ushort_t*)(ws + OFF_Z);
    const ushort_t* Wt = (const ushort_t*)(ws + OFF_WT);
    ushort_t* E1s = (ushort_t*)(ws + OFF_E1S);

    int bx = blockIdx.x;
    int c = bx >> 2, nt = bx & 3;
    int tid = threadIdx.x, w = tid >> 6, lane = tid & 63, q = lane >> 4, r = lane & 15;
    int wr = w >> 1, wc = w & 1;
    int l8 = lane >> 3, srcg = (lane & 7) ^ l8;

    const ushort_t* Xb = Z + (long)c * 64 * 1536 + 512;   // pitch 1536

    f32x4 acc[2][4];
#pragma unroll
    for (int a1 = 0; a1 < 2; a1++)
#pragma unroll
        for (int b1 = 0; b1 < 4; b1++) acc[a1][b1] = (f32x4){0.f, 0.f, 0.f, 0.f};

    for (int s = 0; s < 16; s++) {
        int k0 = s * 64;
#pragma unroll
        for (int i = 0; i < 2; i++) {
            int row = i * 32 + w * 8 + l8;
            gll16(Xb + (long)row * 1536 + k0 + srcg * 8, &Alds[i * 2048 + w * 512]);
        }
        const ushort_t* Yb = Wt + (long)(7 - (s >> 1)) * 65536 + (s & 1) * 64;
#pragma unroll
        for (int i = 0; i < 4; i++) {
            int row = i * 32 + w * 8 + l8;
            gll16(Yb + (long)(nt * 128 + row) * 128 + srcg * 8, &Blds[i * 2048 + w * 512]);
        }
        __syncthreads();
#pragma unroll
        for (int kt = 0; kt < 2; kt++) {
            int g2 = kt * 4 + q;
            bf16x8 a[2], b[4];
#pragma unroll
            for (int mi = 0; mi < 2; mi++) {
                int row = wr * 32 + mi * 16 + r;
                a[mi] = *(bf16x8*)&Alds[row * 64 + ((g2 ^ (row & 7)) << 3)];
            }
#pragma unroll
            for (int nj = 0; nj < 4; nj++) {
                int row = wc * 64 + nj * 16 + r;
                b[nj] = *(bf16x8*)&Blds[row * 64 + ((g2 ^ (row & 7)) << 3)];
            }
#pragma unroll
            for (int mi = 0; mi < 2; mi++)
#pragma unroll
                for (int nj = 0; nj < 4; nj++)
                    acc[mi][nj] = MFMA16(a[mi], b[nj], acc[mi][nj]);
        }
        __syncthreads();
    }

#pragma unroll
    for (int mi = 0; mi < 2; mi++)
#pragma unroll
        for (int nj = 0; nj < 4; nj++) {
            int m = wr * 32 + mi * 16 + q * 4;
            int n = nt * 128 + wc * 64 + nj * 16 + r;
#pragma unroll
            for (int v = 0; v < 4; v++)
                E1s[(long)c * 32768 + (long)(m + v) * 512 + n] = f2bf(acc[mi][nj][v]);
        }
}

// ---------------------------------------------------------------------------
// e2g: E2[g] = sum_{t=0..7} E1[8g+t].A^{8(7-t)} -> E2slab[1+g]  (t=7 -> I)
// grid 512: g = bx>>5, mb = (bx>>4)&1, ntb = bx&15.  32m x 32n, 64 K-steps.
// ---------------------------------------------------------------------------
__global__ __launch_bounds__(256, 5) void e2g(char* __restrict__ ws) {
    __shared__ ushort_t Alds[32 * 64];
    __shared__ ushort_t Blds[32 * 64];
    const ushort_t* At  = (const ushort_t*)(ws + OFF_AT);
    const ushort_t* E1s = (const ushort_t*)(ws + OFF_E1S);
    ushort_t* E2s = (ushort_t*)(ws + OFF_E2S);

    int bx = blockIdx.x;
    int g = bx >> 5, mb = (bx >> 4) & 1, ntb = bx & 15;
    int tid = threadIdx.x, w = tid >> 6, lane = tid & 63, q = lane >> 4, r = lane & 15;
    int wr = w >> 1, wc = w & 1;
    int l8 = lane >> 3, srcg = (lane & 7) ^ l8;

    f32x4 acc = (f32x4){0.f, 0.f, 0.f, 0.f};

    for (int s = 0; s < 64; s++) {
        int t = s >> 3, k0 = (s & 7) * 64;
        const ushort_t* Xp = E1s + (long)(8 * g + t) * 32768 + (long)mb * 32 * 512;
        const ushort_t* Yb = At + (long)slot_of(8 * (7 - t)) * 262144;
        {
            int row = w * 8 + l8;   // 0..31
            gll16(Xp + (long)row * 512 + k0 + srcg * 8, &Alds[w * 512]);
            gll16(Yb + (long)(ntb * 32 + row) * 512 + k0 + srcg * 8, &Blds[w * 512]);
        }
        __syncthreads();
#pragma unroll
        for (int kt = 0; kt < 2; kt++) {
            int g2 = kt * 4 + q;
            int arow = wr * 16 + r;
            bf16x8 a = *(bf16x8*)&Alds[arow * 64 + ((g2 ^ (arow & 7)) << 3)];
            int brow = wc * 16 + r;
            bf16x8 b = *(bf16x8*)&Blds[brow * 64 + ((g2 ^ (brow & 7)) << 3)];
            acc = MFMA16(a, b, acc);
        }
        __syncthreads();
    }

    {
        int m = mb * 32 + wr * 16 + q * 4;
        int n = ntb * 32 + wc * 16 + r;
#pragma unroll
        for (int v = 0; v < 4; v++)
            E2s[(long)(1 + g) * 32768 + (long)(m + v) * 512 + n] = f2bf(acc[v]);
    }
}

// ---------------------------------------------------------------------------
// s1x: S1[c'] = E2slab[g].A^{8j} + [j==0 && g>=1] E2slab[g-1].A^64
//             + sum_{t<j} E1[8g+t].A^{8(j-1-t)}      (c' = 8g+j)
// c' in 0..128 (c'=128: g=16,j=0 -> E2[15] + E2[14].A^64).
// Writes: Z state cols (c'<=127, bf16) AND dout[t=8c'-1] (c'>=1, fp32).
// grid 516.  j-BALANCED mapping for c'<128.
// ---------------------------------------------------------------------------
__global__ __launch_bounds__(256, 5) void s1x(float* __restrict__ dout,
                                              char* __restrict__ ws) {
    __shared__ ushort_t Alds[64 * 64];
    __shared__ ushort_t Blds[128 * 64];
    const ushort_t* At  = (const ushort_t*)(ws + OFF_AT);
    const ushort_t* E1s = (const ushort_t*)(ws + OFF_E1S);
    const ushort_t* E2s = (const ushort_t*)(ws + OFF_E2S);
    ushort_t* Z = (ushort_t*)(ws + OFF_Z);

    int bx = blockIdx.x;
    int t0 = bx >> 2, nt = bx & 3;
    int g, j;
    if (t0 == 128) { g = 16; j = 0; }
    else {
        g = t0 >> 3;
        int jj = t0 & 7;
        j = (g >= 8) ? (7 - jj) : jj;    // balance heavy/light across CUs
    }
    int c = g * 8 + j;
    int extra = (j == 0 && g >= 1) ? 1 : 0;
    int nterms = 1 + extra + j;
    int S = nterms * 8;
    int tid = threadIdx.x, w = tid >> 6, lane = tid & 63, q = lane >> 4, r = lane & 15;
    int wr = w >> 1, wc = w & 1;
    int l8 = lane >> 3, srcg = (lane & 7) ^ l8;

    auto xptr = [&](int t) -> const ushort_t* {
        if (t == 0) return E2s + (long)g * 32768;
        if (extra && t == 1) return E2s + (long)(g - 1) * 32768;
        return E1s + (long)(8 * g + t - 1 - extra) * 32768;
    };
    auto yptr = [&](int t) -> const ushort_t* {
        int p = (t == 0) ? 8 * j : ((extra && t == 1) ? 64 : 8 * (j - t + extra));
        return At + (long)slot_of(p) * 262144;
    };

    f32x4 acc[2][4];
#pragma unroll
    for (int a1 = 0; a1 < 2; a1++)
#pragma unroll
        for (int b1 = 0; b1 < 4; b1++) acc[a1][b1] = (f32x4){0.f, 0.f, 0.f, 0.f};

    for (int s = 0; s < S; s++) {
        int t = s >> 3, k0 = (s & 7) * 64;
        const ushort_t* Xp = xptr(t);
        const ushort_t* Yb = yptr(t);
#pragma unroll
        for (int i = 0; i < 2; i++) {
            int row = i * 32 + w * 8 + l8;
            gll16(Xp + (long)row * 512 + k0 + srcg * 8, &Alds[i * 2048 + w * 512]);
        }
#pragma unroll
        for (int i = 0; i < 4; i++) {
            int row = i * 32 + w * 8 + l8;
            gll16(Yb + (long)(nt * 128 + row) * 512 + k0 + srcg * 8, &Blds[i * 2048 + w * 512]);
        }
        __syncthreads();
#pragma unroll
        for (int kt = 0; kt < 2; kt++) {
            int g2 = kt * 4 + q;
            bf16x8 a[2], b[4];
#pragma unroll
            for (int mi = 0; mi < 2; mi++) {
                int row = wr * 32 + mi * 16 + r;
                a[mi] = *(bf16x8*)&Alds[row * 64 + ((g2 ^ (row & 7)) << 3)];
            }
#pragma unroll
            for (int nj = 0; nj < 4; nj++) {
                int row = wc * 64 + nj * 16 + r;
                b[nj] = *(bf16x8*)&Blds[row * 64 + ((g2 ^ (row & 7)) << 3)];
            }
#pragma unroll
            for (int mi = 0; mi < 2; mi++)
#pragma unroll
                for (int nj = 0; nj < 4; nj++)
                    acc[mi][nj] = MFMA16(a[mi], b[nj], acc[mi][nj]);
        }
        __syncthreads();
    }

#pragma unroll
    for (int mi = 0; mi < 2; mi++)
#pragma unroll
        for (int nj = 0; nj < 4; nj++) {
            int m = wr * 32 + mi * 16 + q * 4;
            int n = nt * 128 + wc * 64 + nj * 16 + r;
#pragma unroll
            for (int v = 0; v < 4; v++) {
                float val = acc[mi][nj][v];
                int row = m + v;
                if (c < 128)
                    Z[(long)(c * 64 + row) * 1536 + n] = f2bf(val);
                if (c >= 1)
                    dout[(long)row * 524288 + (long)(8 * c - 1) * 512 + n] = val;
            }
        }
}

// ---------------------------------------------------------------------------
// outg: out = Z[:, :K_k] . [At[k+1] | Wt]^T for k=0..6 (k=7 done by s1x).
// grid 1792: nt = bx/448, k = (bx%448)>>6, mt = bx&63.  128x128, stage-both.
// ---------------------------------------------------------------------------
__global__ __launch_bounds__(256, 5) void outg(float* __restrict__ dout,
                                               char* __restrict__ ws) {
    __shared__ ushort_t Alds[128 * 64];
    __shared__ ushort_t Blds[128 * 64];
    const ushort_t* Z  = (const ushort_t*)(ws + OFF_Z);
    const ushort_t* At = (const ushort_t*)(ws + OFF_AT);
    const ushort_t* Wt = (const ushort_t*)(ws + OFF_WT);

    int bx = blockIdx.x;
    int nt = bx / 448;
    int rem = bx - nt * 448;
    int k = rem >> 6;
    int mt = rem & 63;
    int tid = threadIdx.x, w = tid >> 6, lane = tid & 63, q = lane >> 4, r = lane & 15;
    int wr = w >> 1, wc = w & 1;
    int l8 = lane >> 3, srcg = (lane & 7) ^ l8;

    const ushort_t* Xb = Z + (long)mt * 128 * 1536;
    const ushort_t* Ya = At + (long)slot_of(k + 1) * 262144;
    int Ks = 8 + 2 * (k + 1);

    f32x4 acc[4][4];
#pragma unroll
    for (int a1 = 0; a1 < 4; a1++)
#pragma unroll
        for (int b1 = 0; b1 < 4; b1++) acc[a1][b1] = (f32x4){0.f, 0.f, 0.f, 0.f};

    for (int s = 0; s < Ks; s++) {
        int k0 = s * 64;
#pragma unroll
        for (int i = 0; i < 4; i++) {
            int row = i * 32 + w * 8 + l8;
            gll16(Xb + (long)row * 1536 + k0 + srcg * 8, &Alds[i * 2048 + w * 512]);
        }
        if (k0 < 512) {
#pragma unroll
            for (int i = 0; i < 4; i++) {
                int row = i * 32 + w * 8 + l8;
                gll16(Ya + (long)(nt * 128 + row) * 512 + k0 + srcg * 8, &Blds[i * 2048 + w * 512]);
            }
        } else {
            int uc = k0 - 512;
            const ushort_t* Yb = Wt + (long)(k - (uc >> 7)) * 65536 + (uc & 127);
#pragma unroll
            for (int i = 0; i < 4; i++) {
                int row = i * 32 + w * 8 + l8;
                gll16(Yb + (long)(nt * 128 + row) * 128 + srcg * 8, &Blds[i * 2048 + w * 512]);
            }
        }
        __syncthreads();
#pragma unroll
        for (int kt = 0; kt < 2; kt++) {
            int g2 = kt * 4 + q;
            bf16x8 a[4], b[4];
#pragma unroll
            for (int mi = 0; mi < 4; mi++) {
                int row = wr * 64 + mi * 16 + r;
                a[mi] = *(bf16x8*)&Alds[row * 64 + ((g2 ^ (row & 7)) << 3)];
            }
#pragma unroll
            for (int nj = 0; nj < 4; nj++) {
                int row = wc * 64 + nj * 16 + r;
                b[nj] = *(bf16x8*)&Blds[row * 64 + ((g2 ^ (row & 7)) << 3)];
            }
#pragma unroll
            for (int mi = 0; mi < 4; mi++)
#pragma unroll
                for (int nj = 0; nj < 4; nj++)
                    acc[mi][nj] = MFMA16(a[mi], b[nj], acc[mi][nj]);
        }
        __syncthreads();
    }

#pragma unroll
    for (int mi = 0; mi < 4; mi++) {
        int m = mt * 128 + wr * 64 + mi * 16 + q * 4;
#pragma unroll
        for (int nj = 0; nj < 4; nj++) {
            int n = nt * 128 + wc * 64 + nj * 16 + r;
#pragma unroll
            for (int v = 0; v < 4; v++) {
                int mm = m + v;
                dout[(long)(mm & 63) * 524288 + (long)(((mm >> 6) << 3) + k) * 512 + n] = acc[mi][nj][v];
            }
        }
    }
}

// ---------------------------------------------------------------------------
extern "C" void kernel_launch(void* const* d_in, const int* in_sizes, int n_in,
                              void* d_out, int out_size, void* d_ws, size_t ws_size,
                              hipStream_t stream) {
    const float* x0 = (const float*)d_in[0];
    const float* us = (const float*)d_in[1];
    const float* A  = (const float*)d_in[2];
    const float* B  = (const float*)d_in[3];
    float* dout = (float*)d_out;
    char* ws = (char*)d_ws;

    prep_kernel<<<2048, 256, 0, stream>>>(A, ws);

    // power ladder, grid 256 each stage:
    //   stage 0 riders: B/x0/identity (umode 1)
    //   stage 3 carries wk (blocks 64..127); u-pack rides stages 1,3,4,5
    const int stdual[6]  = {1, 1, 1, 1, 1, 0};
    const int stwk[6]    = {0, 0, 0, 64, 0, 0};
    const int stub[6]    = {64, 128, 0, 128, 128, 128};    // ubase (0 = none)
    const int stum[6]    = {1, 0, 0, 0, 0, 0};             // umode
    const int stus[6]    = {0, 0, 0, 262144, 524288, 786432};
    const int stue[6]    = {0, 262144, 0, 524288, 786432, 1048576};
    const int stpw[6]    = {64, 128, 256, 64, 128, 128};
    const int std_[6][4] = {{2,0,0,0},{3,4,0,0},{5,6,7,8},{16,0,0,0},{24,32,0,0},{40,48,56,64}};
    const int stm[6][4]  = {{1,0,0,0},{2,2,0,0},{4,4,4,4},{8,0,0,0},{16,16,0,0},{32,32,32,32}};
    const int sti[6][4]  = {{1,0,0,0},{1,2,0,0},{1,2,3,4},{8,0,0,0},{8,16,0,0},{8,16,24,32}};
    for (int s = 0; s < 6; s++) {
        int4 dd = {std_[s][0], std_[s][1], std_[s][2], std_[s][3]};
        int4 mm = {stm[s][0], stm[s][1], stm[s][2], stm[s][3]};
        int4 ii = {sti[s][0], sti[s][1], sti[s][2], sti[s][3]};
        int blocks = (stub[s] > 0) ? 256 : stpw[s] + stwk[s];
        pow_stage<<<blocks, 256, 0, stream>>>(ws, us, x0, B, dd, mm, ii,
                                              stdual[s], stwk[s], stub[s],
                                              stum[s], stus[s], stue[s]);
    }

    e1g<<<512, 256, 0, stream>>>(ws);           // E1 -> E1slab
    e2g<<<512, 256, 0, stream>>>(ws);           // E2 -> E2slab[1+g]
    s1x<<<516, 256, 0, stream>>>(dout, ws);     // S1 -> Z state + dout k=7 slices
    outg<<<1792, 256, 0, stream>>>(dout, ws);   // outputs k=0..6
}

// Round 16
// 249.382 us; speedup vs baseline: 1.1359x; 1.1359x over previous
//
#include <hip/hip_runtime.h>

// ---------------------------------------------------------------------------
// LinearSSM: x_{t+1} = x_t @ A + u_t @ B   (batch=64, T=1024, n=512, p=128)
// Fully parallel chunked solve.  All heavy GEMMs: proven 2-barrier structure,
// global_load_lds 16B into XOR-swizzled LDS, __launch_bounds__(256,4)
// (VGPR 64 -> 4 blocks/CU; (256,5) measured WORSE: VGPR squeezed to 48,
//  MfmaUtil 37->21%).
//   prep: bf16 casts of A only (2048 blocks)
//   pow stages (grid 256 each): A^2..A^64 dual chains; wk rides stage 3;
//     B/x0/identity ride stage 0; u-pack rides stages 1,3,4,5
//   e1g: E1[c] = u-chunk . Wstack -> E1slab   (512 blocks, 64x128, K=1024)
//   e2g: E2[g] = sum_t E1[8g+t].A^{8(7-t)}    (512 blocks, 32x32, K=4096)
//   s1x: S1[c'] c'=0..128 -> Z state cols (c'<=127) AND dout[t=8c'-1]
//   outg: out = Z[:, :K_k] . [At[k+1] | Wt..]^T for k=0..6
// ---------------------------------------------------------------------------

typedef __attribute__((ext_vector_type(8))) short bf16x8;
typedef __attribute__((ext_vector_type(8))) unsigned short ushort8;
typedef __attribute__((ext_vector_type(4))) float f32x4;
typedef unsigned short ushort_t;

#define MFMA16(a, b, c) __builtin_amdgcn_mfma_f32_16x16x32_bf16(a, b, c, 0, 0, 0)

// workspace layout (bytes)
#define OFF_AT  0UL           // 17 slots (A^p)^T bf16 [512][512]; slot16 = I
#define OFF_AU  8912896UL     // 12 slots A^p bf16 [512][512]
#define OFF_BT  15204352UL    // B^T bf16 [512][128]
#define OFF_BU  15335424UL    // B   bf16 [128][512]
#define OFF_WT  15466496UL    // 8 x (B.A^p)^T bf16 [512][128]
#define OFF_Z   16515072UL    // [8192][1536] bf16: [S1 | u-chunk]
#define OFF_E1S 41680896UL    // [128][64][512] bf16 : E1 slab
#define OFF_E2S 50069504UL    // [17][64][512] bf16  : slot0 = x0, 1+g = E2[g]

__host__ __device__ __forceinline__ int slot_of(int p) {
    if (p == 0) return 16;          // identity
    if (p <= 8) return p - 1;
    return 7 + (p >> 3);            // 16,24,..,64 -> 9..15
}

__device__ __forceinline__ unsigned short f2bf(float f) {
    union { float f; unsigned u; } v; v.f = f;
    unsigned r = v.u + 0x7FFFu + ((v.u >> 16) & 1u);
    return (unsigned short)(r >> 16);
}

__device__ __forceinline__ int sel4(int4 v, int p) {
    return p == 0 ? v.x : p == 1 ? v.y : p == 2 ? v.z : v.w;
}

typedef __attribute__((address_space(3))) unsigned int as3_u32;
typedef __attribute__((address_space(1))) const unsigned int as1_u32;
__device__ __forceinline__ void gll16(const void* g, void* l) {
    __builtin_amdgcn_global_load_lds((as1_u32*)g, (as3_u32*)l, 16, 0, 0);
}

// ---------------------------------------------------------------------------
// prep: bf16 casts of A only.  524288 items, grid 2048.
// ---------------------------------------------------------------------------
__global__ __launch_bounds__(256) void prep_kernel(const float* __restrict__ A,
                                                   char* __restrict__ ws) {
    ushort_t* At1 = (ushort_t*)(ws + OFF_AT);
    ushort_t* Au1 = (ushort_t*)(ws + OFF_AU);
    long idx = (long)blockIdx.x * 256 + threadIdx.x;
    if (idx < 262144) {
        Au1[idx] = f2bf(A[idx]);                          // coalesced r/w
    } else {
        long gi = idx - 262144;
        int n = (int)(gi >> 9), k = (int)(gi & 511);
        At1[gi] = f2bf(A[(long)k * 512 + n]);             // scattered read, coal. write
    }
}

// ---------------------------------------------------------------------------
// pow tile body: At[d] = At[m] .NT Au[i] (prod 0); Au[d] = Au[i] .NT At[m] (1)
// ---------------------------------------------------------------------------
__device__ __forceinline__ void pow_tile(char* __restrict__ ws, ushort_t* ldsX,
                                         int d, int m_, int i_, int prod,
                                         int mb, int nb) {
    ushort_t* At = (ushort_t*)(ws + OFF_AT);
    ushort_t* Au = (ushort_t*)(ws + OFF_AU);
    const ushort_t *Xp, *Yp; ushort_t* outp;
    if (prod == 0) { Xp = At + (long)slot_of(m_) * 262144; Yp = Au + (long)slot_of(i_) * 262144; outp = At + (long)slot_of(d) * 262144; }
    else           { Xp = Au + (long)slot_of(i_) * 262144; Yp = At + (long)slot_of(m_) * 262144; outp = Au + (long)slot_of(d) * 262144; }

    int tid = threadIdx.x, w = tid >> 6, lane = tid & 63, q = lane >> 4, r = lane & 15;

    for (int i2 = tid; i2 < 64 * 64; i2 += 256) {
        int row = i2 >> 6, c8 = i2 & 63;
        ushort8 v = *(const ushort8*)(Xp + (long)(mb * 64 + row) * 512 + c8 * 8);
        *(ushort8*)&ldsX[row * 512 + ((c8 ^ (row & 7)) << 3)] = v;
    }
    __syncthreads();

    f32x4 acc[4][2];
    for (int a1 = 0; a1 < 4; a1++) for (int b1 = 0; b1 < 2; b1++) acc[a1][b1] = (f32x4){0.f, 0.f, 0.f, 0.f};

    int n0 = nb * 128 + w * 32;
    for (int kt = 0; kt < 16; kt++) {
        bf16x8 b0 = *(const bf16x8*)(Yp + (long)(n0 + r) * 512 + kt * 32 + q * 8);
        bf16x8 b1 = *(const bf16x8*)(Yp + (long)(n0 + 16 + r) * 512 + kt * 32 + q * 8);
        int g2 = kt * 4 + q;
#pragma unroll
        for (int mi = 0; mi < 4; mi++) {
            int row = mi * 16 + r;
            bf16x8 a = *(bf16x8*)&ldsX[row * 512 + ((g2 ^ (row & 7)) << 3)];
            acc[mi][0] = MFMA16(a, b0, acc[mi][0]);
            acc[mi][1] = MFMA16(a, b1, acc[mi][1]);
        }
    }
    for (int mi = 0; mi < 4; mi++) for (int nj = 0; nj < 2; nj++) {
        int m = mb * 64 + mi * 16 + q * 4, n = n0 + nj * 16 + r;
        for (int v = 0; v < 4; v++) outp[(long)(m + v) * 512 + n] = f2bf(acc[mi][nj][v]);
    }
}

// ---------------------------------------------------------------------------
// wk tile body: Wt[p] = (B.A^p)^T, p = 7-k8;  k8==7 -> copy B^T into Wt[0].
// ---------------------------------------------------------------------------
__device__ __forceinline__ void wk_tile(char* __restrict__ ws, ushort_t* ldsX,
                                        int k8, int mb) {
    ushort_t* At = (ushort_t*)(ws + OFF_AT);
    ushort_t* Bu = (ushort_t*)(ws + OFF_BU);
    ushort_t* Bt = (ushort_t*)(ws + OFF_BT);
    ushort_t* Wt = (ushort_t*)(ws + OFF_WT);

    int tid = threadIdx.x, w = tid >> 6, lane = tid & 63, q = lane >> 4, r = lane & 15;

    if (k8 == 7) {  // p = 0: Wt[0] = B^T
        for (int i2 = tid; i2 < 64 * 32; i2 += 256) {
            int row = i2 >> 5, c4 = i2 & 31;
            ushort4 v = *(const ushort4*)(Bt + (long)(mb * 64 + row) * 128 + c4 * 4);
            *(ushort4*)(Wt + (long)(mb * 64 + row) * 128 + c4 * 4) = v;
        }
        return;
    }

    int p = 7 - k8;
    const ushort_t* Xp = At + (long)slot_of(p) * 262144;
    for (int i2 = tid; i2 < 64 * 64; i2 += 256) {
        int row = i2 >> 6, c8 = i2 & 63;
        ushort8 v = *(const ushort8*)(Xp + (long)(mb * 64 + row) * 512 + c8 * 8);
        *(ushort8*)&ldsX[row * 512 + ((c8 ^ (row & 7)) << 3)] = v;
    }
    __syncthreads();

    f32x4 acc[4][2];
    for (int a1 = 0; a1 < 4; a1++) for (int b1 = 0; b1 < 2; b1++) acc[a1][b1] = (f32x4){0.f, 0.f, 0.f, 0.f};

    int n0 = w * 32;
    for (int kt = 0; kt < 16; kt++) {
        bf16x8 b0 = *(const bf16x8*)(Bu + (long)(n0 + r) * 512 + kt * 32 + q * 8);
        bf16x8 b1 = *(const bf16x8*)(Bu + (long)(n0 + 16 + r) * 512 + kt * 32 + q * 8);
        int g2 = kt * 4 + q;
#pragma unroll
        for (int mi = 0; mi < 4; mi++) {
            int row = mi * 16 + r;
            bf16x8 a = *(bf16x8*)&ldsX[row * 512 + ((g2 ^ (row & 7)) << 3)];
            acc[mi][0] = MFMA16(a, b0, acc[mi][0]);
            acc[mi][1] = MFMA16(a, b1, acc[mi][1]);
        }
    }
    ushort_t* Wp = Wt + (long)p * 65536;
    for (int mi = 0; mi < 4; mi++) for (int nj = 0; nj < 2; nj++) {
        int m = mb * 64 + mi * 16 + q * 4, n = n0 + nj * 16 + r;
        for (int v = 0; v < 4; v++) Wp[(long)(m + v) * 128 + n] = f2bf(acc[mi][nj][v]);
    }
}

// ---------------------------------------------------------------------------
// pow_stage: block-partitioned launch (grid 256):
//   [0, wkbase): pow tiles   [wkbase, ubase): wk tiles
//   [ubase, 256): riders -- umode 0: u-pack [ustart,uend); umode 1: B/x0/ident
// ---------------------------------------------------------------------------
__global__ __launch_bounds__(256) void pow_stage(char* __restrict__ ws,
                                                 const float* __restrict__ us,
                                                 const float* __restrict__ x0,
                                                 const float* __restrict__ B,
                                                 int4 dd, int4 mm, int4 ii,
                                                 int dual, int wkbase,
                                                 int ubase, int umode,
                                                 int ustart, int uend) {
    __shared__ ushort_t ldsX[64 * 512];
    int bx = blockIdx.x;

    if (ubase > 0 && bx >= ubase) {
        int tid = threadIdx.x;
        int nthr = (256 - ubase) * 256;
        if (umode == 0) {
            ushort_t* Z = (ushort_t*)(ws + OFF_Z);
            for (long gi = ustart + (long)(bx - ubase) * 256 + tid; gi < uend; gi += nthr) {
                int row = (int)(gi >> 7), g8 = (int)(gi & 127);
                int c = row >> 6, b = row & 63;
                const float* src = us + (long)b * 131072 + c * 1024 + g8 * 8;
                float4 v0 = *(const float4*)src;
                float4 v1 = *(const float4*)(src + 4);
                ushort8 h = { f2bf(v0.x), f2bf(v0.y), f2bf(v0.z), f2bf(v0.w),
                              f2bf(v1.x), f2bf(v1.y), f2bf(v1.z), f2bf(v1.w) };
                *(ushort8*)(Z + (long)row * 1536 + 512 + g8 * 8) = h;
            }
        } else {
            ushort_t* Bt  = (ushort_t*)(ws + OFF_BT);
            ushort_t* Bu  = (ushort_t*)(ws + OFF_BU);
            ushort_t* X0b = (ushort_t*)(ws + OFF_E2S);
            ushort_t* At1 = (ushort_t*)(ws + OFF_AT);
            for (long i = (long)(bx - ubase) * 256 + tid; i < 331776; i += nthr) {
                if (i < 65536) {
                    int kp = (int)(i >> 9), n = (int)(i & 511);
                    ushort_t v = f2bf(B[i]);
                    Bt[(long)n * 128 + kp] = v;
                    Bu[i] = v;
                } else if (i < 69632) {
                    long gi = i - 65536;
                    long e0 = gi * 8;
                    float4 v0 = *(const float4*)(x0 + e0);
                    float4 v1 = *(const float4*)(x0 + e0 + 4);
                    ushort8 h = { f2bf(v0.x), f2bf(v0.y), f2bf(v0.z), f2bf(v0.w),
                                  f2bf(v1.x), f2bf(v1.y), f2bf(v1.z), f2bf(v1.w) };
                    *(ushort8*)(X0b + e0) = h;
                } else {
                    long gi2 = i - 69632;
                    int n = (int)(gi2 >> 9), k2 = (int)(gi2 & 511);
                    At1[(long)16 * 262144 + gi2] = (n == k2) ? (ushort_t)0x3F80 : (ushort_t)0;
                }
            }
        }
        return;
    }
    if (wkbase > 0 && bx >= wkbase) {
        int widx = bx - wkbase;
        wk_tile(ws, ldsX, widx >> 3, widx & 7);
        return;
    }

    int nb = bx & 3, mb = (bx >> 2) & 7;
    int prod, pair;
    if (dual) { prod = (bx >> 5) & 1; pair = bx >> 6; }
    else      { prod = 0;             pair = bx >> 5; }
    int d = sel4(dd, pair), m_ = sel4(mm, pair), i_ = sel4(ii, pair);
    pow_tile(ws, ldsX, d, m_, i_, prod, mb, nb);
}

// ---------------------------------------------------------------------------
// e1g: E1[c] = Zu-chunk [64 x 1024] .NT Wstack -> E1slab[c]
// grid 512: c = bx>>2, nt = bx&3.  64m x 128n, 16 K-steps, stage-both.
// ---------------------------------------------------------------------------
__global__ __launch_bounds__(256, 4) void e1g(char* __restrict__ ws) {
    __shared__ ushort_t Alds[64 * 64];
    __shared__ ushort_t Blds[128 * 64];
    const ushort_t* Z  = (const ushort_t*)(ws + OFF_Z);
    const ushort_t* Wt = (const ushort_t*)(ws + OFF_WT);
    ushort_t* E1s = (ushort_t*)(ws + OFF_E1S);

    int bx = blockIdx.x;
    int c = bx >> 2, nt = bx & 3;
    int tid = threadIdx.x, w = tid >> 6, lane = tid & 63, q = lane >> 4, r = lane & 15;
    int wr = w >> 1, wc = w & 1;
    int l8 = lane >> 3, srcg = (lane & 7) ^ l8;

    const ushort_t* Xb = Z + (long)c * 64 * 1536 + 512;   // pitch 1536

    f32x4 acc[2][4];
#pragma unroll
    for (int a1 = 0; a1 < 2; a1++)
#pragma unroll
        for (int b1 = 0; b1 < 4; b1++) acc[a1][b1] = (f32x4){0.f, 0.f, 0.f, 0.f};

    for (int s = 0; s < 16; s++) {
        int k0 = s * 64;
#pragma unroll
        for (int i = 0; i < 2; i++) {
            int row = i * 32 + w * 8 + l8;
            gll16(Xb + (long)row * 1536 + k0 + srcg * 8, &Alds[i * 2048 + w * 512]);
        }
        const ushort_t* Yb = Wt + (long)(7 - (s >> 1)) * 65536 + (s & 1) * 64;
#pragma unroll
        for (int i = 0; i < 4; i++) {
            int row = i * 32 + w * 8 + l8;
            gll16(Yb + (long)(nt * 128 + row) * 128 + srcg * 8, &Blds[i * 2048 + w * 512]);
        }
        __syncthreads();
#pragma unroll
        for (int kt = 0; kt < 2; kt++) {
            int g2 = kt * 4 + q;
            bf16x8 a[2], b[4];
#pragma unroll
            for (int mi = 0; mi < 2; mi++) {
                int row = wr * 32 + mi * 16 + r;
                a[mi] = *(bf16x8*)&Alds[row * 64 + ((g2 ^ (row & 7)) << 3)];
            }
#pragma unroll
            for (int nj = 0; nj < 4; nj++) {
                int row = wc * 64 + nj * 16 + r;
                b[nj] = *(bf16x8*)&Blds[row * 64 + ((g2 ^ (row & 7)) << 3)];
            }
#pragma unroll
            for (int mi = 0; mi < 2; mi++)
#pragma unroll
                for (int nj = 0; nj < 4; nj++)
                    acc[mi][nj] = MFMA16(a[mi], b[nj], acc[mi][nj]);
        }
        __syncthreads();
    }

#pragma unroll
    for (int mi = 0; mi < 2; mi++)
#pragma unroll
        for (int nj = 0; nj < 4; nj++) {
            int m = wr * 32 + mi * 16 + q * 4;
            int n = nt * 128 + wc * 64 + nj * 16 + r;
#pragma unroll
            for (int v = 0; v < 4; v++)
                E1s[(long)c * 32768 + (long)(m + v) * 512 + n] = f2bf(acc[mi][nj][v]);
        }
}

// ---------------------------------------------------------------------------
// e2g: E2[g] = sum_{t=0..7} E1[8g+t].A^{8(7-t)} -> E2slab[1+g]  (t=7 -> I)
// grid 512: g = bx>>5, mb = (bx>>4)&1, ntb = bx&15.  32m x 32n, 64 K-steps.
// ---------------------------------------------------------------------------
__global__ __launch_bounds__(256, 4) void e2g(char* __restrict__ ws) {
    __shared__ ushort_t Alds[32 * 64];
    __shared__ ushort_t Blds[32 * 64];
    const ushort_t* At  = (const ushort_t*)(ws + OFF_AT);
    const ushort_t* E1s = (const ushort_t*)(ws + OFF_E1S);
    ushort_t* E2s = (ushort_t*)(ws + OFF_E2S);

    int bx = blockIdx.x;
    int g = bx >> 5, mb = (bx >> 4) & 1, ntb = bx & 15;
    int tid = threadIdx.x, w = tid >> 6, lane = tid & 63, q = lane >> 4, r = lane & 15;
    int wr = w >> 1, wc = w & 1;
    int l8 = lane >> 3, srcg = (lane & 7) ^ l8;

    f32x4 acc = (f32x4){0.f, 0.f, 0.f, 0.f};

    for (int s = 0; s < 64; s++) {
        int t = s >> 3, k0 = (s & 7) * 64;
        const ushort_t* Xp = E1s + (long)(8 * g + t) * 32768 + (long)mb * 32 * 512;
        const ushort_t* Yb = At + (long)slot_of(8 * (7 - t)) * 262144;
        {
            int row = w * 8 + l8;   // 0..31
            gll16(Xp + (long)row * 512 + k0 + srcg * 8, &Alds[w * 512]);
            gll16(Yb + (long)(ntb * 32 + row) * 512 + k0 + srcg * 8, &Blds[w * 512]);
        }
        __syncthreads();
#pragma unroll
        for (int kt = 0; kt < 2; kt++) {
            int g2 = kt * 4 + q;
            int arow = wr * 16 + r;
            bf16x8 a = *(bf16x8*)&Alds[arow * 64 + ((g2 ^ (arow & 7)) << 3)];
            int brow = wc * 16 + r;
            bf16x8 b = *(bf16x8*)&Blds[brow * 64 + ((g2 ^ (brow & 7)) << 3)];
            acc = MFMA16(a, b, acc);
        }
        __syncthreads();
    }

    {
        int m = mb * 32 + wr * 16 + q * 4;
        int n = ntb * 32 + wc * 16 + r;
#pragma unroll
        for (int v = 0; v < 4; v++)
            E2s[(long)(1 + g) * 32768 + (long)(m + v) * 512 + n] = f2bf(acc[v]);
    }
}

// ---------------------------------------------------------------------------
// s1x: S1[c'] = E2slab[g].A^{8j} + [j==0 && g>=1] E2slab[g-1].A^64
//             + sum_{t<j} E1[8g+t].A^{8(j-1-t)}      (c' = 8g+j)
// c' in 0..128 (c'=128: g=16,j=0 -> E2[15] + E2[14].A^64).
// Writes: Z state cols (c'<=127, bf16) AND dout[t=8c'-1] (c'>=1, fp32).
// grid 516.  j-BALANCED mapping for c'<128.
// ---------------------------------------------------------------------------
__global__ __launch_bounds__(256, 4) void s1x(float* __restrict__ dout,
                                              char* __restrict__ ws) {
    __shared__ ushort_t Alds[64 * 64];
    __shared__ ushort_t Blds[128 * 64];
    const ushort_t* At  = (const ushort_t*)(ws + OFF_AT);
    const ushort_t* E1s = (const ushort_t*)(ws + OFF_E1S);
    const ushort_t* E2s = (const ushort_t*)(ws + OFF_E2S);
    ushort_t* Z = (ushort_t*)(ws + OFF_Z);

    int bx = blockIdx.x;
    int t0 = bx >> 2, nt = bx & 3;
    int g, j;
    if (t0 == 128) { g = 16; j = 0; }
    else {
        g = t0 >> 3;
        int jj = t0 & 7;
        j = (g >= 8) ? (7 - jj) : jj;    // balance heavy/light across CUs
    }
    int c = g * 8 + j;
    int extra = (j == 0 && g >= 1) ? 1 : 0;
    int nterms = 1 + extra + j;
    int S = nterms * 8;
    int tid = threadIdx.x, w = tid >> 6, lane = tid & 63, q = lane >> 4, r = lane & 15;
    int wr = w >> 1, wc = w & 1;
    int l8 = lane >> 3, srcg = (lane & 7) ^ l8;

    auto xptr = [&](int t) -> const ushort_t* {
        if (t == 0) return E2s + (long)g * 32768;
        if (extra && t == 1) return E2s + (long)(g - 1) * 32768;
        return E1s + (long)(8 * g + t - 1 - extra) * 32768;
    };
    auto yptr = [&](int t) -> const ushort_t* {
        int p = (t == 0) ? 8 * j : ((extra && t == 1) ? 64 : 8 * (j - t + extra));
        return At + (long)slot_of(p) * 262144;
    };

    f32x4 acc[2][4];
#pragma unroll
    for (int a1 = 0; a1 < 2; a1++)
#pragma unroll
        for (int b1 = 0; b1 < 4; b1++) acc[a1][b1] = (f32x4){0.f, 0.f, 0.f, 0.f};

    for (int s = 0; s < S; s++) {
        int t = s >> 3, k0 = (s & 7) * 64;
        const ushort_t* Xp = xptr(t);
        const ushort_t* Yb = yptr(t);
#pragma unroll
        for (int i = 0; i < 2; i++) {
            int row = i * 32 + w * 8 + l8;
            gll16(Xp + (long)row * 512 + k0 + srcg * 8, &Alds[i * 2048 + w * 512]);
        }
#pragma unroll
        for (int i = 0; i < 4; i++) {
            int row = i * 32 + w * 8 + l8;
            gll16(Yb + (long)(nt * 128 + row) * 512 + k0 + srcg * 8, &Blds[i * 2048 + w * 512]);
        }
        __syncthreads();
#pragma unroll
        for (int kt = 0; kt < 2; kt++) {
            int g2 = kt * 4 + q;
            bf16x8 a[2], b[4];
#pragma unroll
            for (int mi = 0; mi < 2; mi++) {
                int row = wr * 32 + mi * 16 + r;
                a[mi] = *(bf16x8*)&Alds[row * 64 + ((g2 ^ (row & 7)) << 3)];
            }
#pragma unroll
            for (int nj = 0; nj < 4; nj++) {
                int row = wc * 64 + nj * 16 + r;
                b[nj] = *(bf16x8*)&Blds[row * 64 + ((g2 ^ (row & 7)) << 3)];
            }
#pragma unroll
            for (int mi = 0; mi < 2; mi++)
#pragma unroll
                for (int nj = 0; nj < 4; nj++)
                    acc[mi][nj] = MFMA16(a[mi], b[nj], acc[mi][nj]);
        }
        __syncthreads();
    }

#pragma unroll
    for (int mi = 0; mi < 2; mi++)
#pragma unroll
        for (int nj = 0; nj < 4; nj++) {
            int m = wr * 32 + mi * 16 + q * 4;
            int n = nt * 128 + wc * 64 + nj * 16 + r;
#pragma unroll
            for (int v = 0; v < 4; v++) {
                float val = acc[mi][nj][v];
                int row = m + v;
                if (c < 128)
                    Z[(long)(c * 64 + row) * 1536 + n] = f2bf(val);
                if (c >= 1)
                    dout[(long)row * 524288 + (long)(8 * c - 1) * 512 + n] = val;
            }
        }
}

// ---------------------------------------------------------------------------
// outg: out = Z[:, :K_k] . [At[k+1] | Wt]^T for k=0..6 (k=7 done by s1x).
// grid 1792: nt = bx/448, k = (bx%448)>>6, mt = bx&63.  128x128, stage-both.
// ---------------------------------------------------------------------------
__global__ __launch_bounds__(256, 4) void outg(float* __restrict__ dout,
                                               char* __restrict__ ws) {
    __shared__ ushort_t Alds[128 * 64];
    __shared__ ushort_t Blds[128 * 64];
    const ushort_t* Z  = (const ushort_t*)(ws + OFF_Z);
    const ushort_t* At = (const ushort_t*)(ws + OFF_AT);
    const ushort_t* Wt = (const ushort_t*)(ws + OFF_WT);

    int bx = blockIdx.x;
    int nt = bx / 448;
    int rem = bx - nt * 448;
    int k = rem >> 6;
    int mt = rem & 63;
    int tid = threadIdx.x, w = tid >> 6, lane = tid & 63, q = lane >> 4, r = lane & 15;
    int wr = w >> 1, wc = w & 1;
    int l8 = lane >> 3, srcg = (lane & 7) ^ l8;

    const ushort_t* Xb = Z + (long)mt * 128 * 1536;
    const ushort_t* Ya = At + (long)slot_of(k + 1) * 262144;
    int Ks = 8 + 2 * (k + 1);

    f32x4 acc[4][4];
#pragma unroll
    for (int a1 = 0; a1 < 4; a1++)
#pragma unroll
        for (int b1 = 0; b1 < 4; b1++) acc[a1][b1] = (f32x4){0.f, 0.f, 0.f, 0.f};

    for (int s = 0; s < Ks; s++) {
        int k0 = s * 64;
#pragma unroll
        for (int i = 0; i < 4; i++) {
            int row = i * 32 + w * 8 + l8;
            gll16(Xb + (long)row * 1536 + k0 + srcg * 8, &Alds[i * 2048 + w * 512]);
        }
        if (k0 < 512) {
#pragma unroll
            for (int i = 0; i < 4; i++) {
                int row = i * 32 + w * 8 + l8;
                gll16(Ya + (long)(nt * 128 + row) * 512 + k0 + srcg * 8, &Blds[i * 2048 + w * 512]);
            }
        } else {
            int uc = k0 - 512;
            const ushort_t* Yb = Wt + (long)(k - (uc >> 7)) * 65536 + (uc & 127);
#pragma unroll
            for (int i = 0; i < 4; i++) {
                int row = i * 32 + w * 8 + l8;
                gll16(Yb + (long)(nt * 128 + row) * 128 + srcg * 8, &Blds[i * 2048 + w * 512]);
            }
        }
        __syncthreads();
#pragma unroll
        for (int kt = 0; kt < 2; kt++) {
            int g2 = kt * 4 + q;
            bf16x8 a[4], b[4];
#pragma unroll
            for (int mi = 0; mi < 4; mi++) {
                int row = wr * 64 + mi * 16 + r;
                a[mi] = *(bf16x8*)&Alds[row * 64 + ((g2 ^ (row & 7)) << 3)];
            }
#pragma unroll
            for (int nj = 0; nj < 4; nj++) {
                int row = wc * 64 + nj * 16 + r;
                b[nj] = *(bf16x8*)&Blds[row * 64 + ((g2 ^ (row & 7)) << 3)];
            }
#pragma unroll
            for (int mi = 0; mi < 4; mi++)
#pragma unroll
                for (int nj = 0; nj < 4; nj++)
                    acc[mi][nj] = MFMA16(a[mi], b[nj], acc[mi][nj]);
        }
        __syncthreads();
    }

#pragma unroll
    for (int mi = 0; mi < 4; mi++) {
        int m = mt * 128 + wr * 64 + mi * 16 + q * 4;
#pragma unroll
        for (int nj = 0; nj < 4; nj++) {
            int n = nt * 128 + wc * 64 + nj * 16 + r;
#pragma unroll
            for (int v = 0; v < 4; v++) {
                int mm = m + v;
                dout[(long)(mm & 63) * 524288 + (long)(((mm >> 6) << 3) + k) * 512 + n] = acc[mi][nj][v];
            }
        }
    }
}

// ---------------------------------------------------------------------------
extern "C" void kernel_launch(void* const* d_in, const int* in_sizes, int n_in,
                              void* d_out, int out_size, void* d_ws, size_t ws_size,
                              hipStream_t stream) {
    const float* x0 = (const float*)d_in[0];
    const float* us = (const float*)d_in[1];
    const float* A  = (const float*)d_in[2];
    const float* B  = (const float*)d_in[3];
    float* dout = (float*)d_out;
    char* ws = (char*)d_ws;

    prep_kernel<<<2048, 256, 0, stream>>>(A, ws);

    // power ladder, grid 256 each stage:
    //   stage 0 riders: B/x0/identity (umode 1)
    //   stage 3 carries wk (blocks 64..127); u-pack rides stages 1,3,4,5
    const int stdual[6]  = {1, 1, 1, 1, 1, 0};
    const int stwk[6]    = {0, 0, 0, 64, 0, 0};
    const int stub[6]    = {64, 128, 0, 128, 128, 128};    // ubase (0 = none)
    const int stum[6]    = {1, 0, 0, 0, 0, 0};             // umode
    const int stus[6]    = {0, 0, 0, 262144, 524288, 786432};
    const int stue[6]    = {0, 262144, 0, 524288, 786432, 1048576};
    const int stpw[6]    = {64, 128, 256, 64, 128, 128};
    const int std_[6][4] = {{2,0,0,0},{3,4,0,0},{5,6,7,8},{16,0,0,0},{24,32,0,0},{40,48,56,64}};
    const int stm[6][4]  = {{1,0,0,0},{2,2,0,0},{4,4,4,4},{8,0,0,0},{16,16,0,0},{32,32,32,32}};
    const int sti[6][4]  = {{1,0,0,0},{1,2,0,0},{1,2,3,4},{8,0,0,0},{8,16,0,0},{8,16,24,32}};
    for (int s = 0; s < 6; s++) {
        int4 dd = {std_[s][0], std_[s][1], std_[s][2], std_[s][3]};
        int4 mm = {stm[s][0], stm[s][1], stm[s][2], stm[s][3]};
        int4 ii = {sti[s][0], sti[s][1], sti[s][2], sti[s][3]};
        int blocks = (stub[s] > 0) ? 256 : stpw[s] + stwk[s];
        pow_stage<<<blocks, 256, 0, stream>>>(ws, us, x0, B, dd, mm, ii,
                                              stdual[s], stwk[s], stub[s],
                                              stum[s], stus[s], stue[s]);
    }

    e1g<<<512, 256, 0, stream>>>(ws);           // E1 -> E1slab
    e2g<<<512, 256, 0, stream>>>(ws);           // E2 -> E2slab[1+g]
    s1x<<<516, 256, 0, stream>>>(dout, ws);     // S1 -> Z state + dout k=7 slices
    outg<<<1792, 256, 0, stream>>>(dout, ws);   // outputs k=0..6
}

// Round 17
// 246.805 us; speedup vs baseline: 1.1478x; 1.0104x over previous
//
#include <hip/hip_runtime.h>

// ---------------------------------------------------------------------------
// LinearSSM: x_{t+1} = x_t @ A + u_t @ B   (batch=64, T=1024, n=512, p=128)
// Fully parallel chunked solve.  All heavy GEMMs: proven 2-barrier structure,
// global_load_lds 16B into XOR-swizzled LDS, __launch_bounds__(256,4)
// (VGPR 64 -> 4 blocks/CU; (256,5) measured WORSE: VGPR squeezed to 48).
//   prep: bf16 casts of A only (2048 blocks)
//   pow stages (grid 256 each): A^2..A^64 dual chains; wk rides stage 3;
//     B/x0/identity ride stage 0; u-pack rides stages 1,3,4,5
//   e1g: E1[c] = u-chunk . Wstack -> E1slab   (512 blocks, 64x128, K=1024)
//   e2g: E2[g] = sum_t E1[8g+t].A^{8(7-t)}    (512 blocks, 32x32, K=4096)
//   s1x: S1[c'] c'=0..128 -> Z state cols (c'<=127) AND dout[t=8c'-1]
//   outg: out = Z[:, :K_k] . [At[k+1] | Wt..]^T for k=0..6
//         (HEAVY-k-FIRST block order: k = 6 - (rem>>6) so the long blocks
//          start in the first resident wave and the tail is light)
// ---------------------------------------------------------------------------

typedef __attribute__((ext_vector_type(8))) short bf16x8;
typedef __attribute__((ext_vector_type(8))) unsigned short ushort8;
typedef __attribute__((ext_vector_type(4))) float f32x4;
typedef unsigned short ushort_t;

#define MFMA16(a, b, c) __builtin_amdgcn_mfma_f32_16x16x32_bf16(a, b, c, 0, 0, 0)

// workspace layout (bytes)
#define OFF_AT  0UL           // 17 slots (A^p)^T bf16 [512][512]; slot16 = I
#define OFF_AU  8912896UL     // 12 slots A^p bf16 [512][512]
#define OFF_BT  15204352UL    // B^T bf16 [512][128]
#define OFF_BU  15335424UL    // B   bf16 [128][512]
#define OFF_WT  15466496UL    // 8 x (B.A^p)^T bf16 [512][128]
#define OFF_Z   16515072UL    // [8192][1536] bf16: [S1 | u-chunk]
#define OFF_E1S 41680896UL    // [128][64][512] bf16 : E1 slab
#define OFF_E2S 50069504UL    // [17][64][512] bf16  : slot0 = x0, 1+g = E2[g]

__host__ __device__ __forceinline__ int slot_of(int p) {
    if (p == 0) return 16;          // identity
    if (p <= 8) return p - 1;
    return 7 + (p >> 3);            // 16,24,..,64 -> 9..15
}

__device__ __forceinline__ unsigned short f2bf(float f) {
    union { float f; unsigned u; } v; v.f = f;
    unsigned r = v.u + 0x7FFFu + ((v.u >> 16) & 1u);
    return (unsigned short)(r >> 16);
}

__device__ __forceinline__ int sel4(int4 v, int p) {
    return p == 0 ? v.x : p == 1 ? v.y : p == 2 ? v.z : v.w;
}

typedef __attribute__((address_space(3))) unsigned int as3_u32;
typedef __attribute__((address_space(1))) const unsigned int as1_u32;
__device__ __forceinline__ void gll16(const void* g, void* l) {
    __builtin_amdgcn_global_load_lds((as1_u32*)g, (as3_u32*)l, 16, 0, 0);
}

// ---------------------------------------------------------------------------
// prep: bf16 casts of A only.  524288 items, grid 2048.
// ---------------------------------------------------------------------------
__global__ __launch_bounds__(256) void prep_kernel(const float* __restrict__ A,
                                                   char* __restrict__ ws) {
    ushort_t* At1 = (ushort_t*)(ws + OFF_AT);
    ushort_t* Au1 = (ushort_t*)(ws + OFF_AU);
    long idx = (long)blockIdx.x * 256 + threadIdx.x;
    if (idx < 262144) {
        Au1[idx] = f2bf(A[idx]);                          // coalesced r/w
    } else {
        long gi = idx - 262144;
        int n = (int)(gi >> 9), k = (int)(gi & 511);
        At1[gi] = f2bf(A[(long)k * 512 + n]);             // scattered read, coal. write
    }
}

// ---------------------------------------------------------------------------
// pow tile body: At[d] = At[m] .NT Au[i] (prod 0); Au[d] = Au[i] .NT At[m] (1)
// ---------------------------------------------------------------------------
__device__ __forceinline__ void pow_tile(char* __restrict__ ws, ushort_t* ldsX,
                                         int d, int m_, int i_, int prod,
                                         int mb, int nb) {
    ushort_t* At = (ushort_t*)(ws + OFF_AT);
    ushort_t* Au = (ushort_t*)(ws + OFF_AU);
    const ushort_t *Xp, *Yp; ushort_t* outp;
    if (prod == 0) { Xp = At + (long)slot_of(m_) * 262144; Yp = Au + (long)slot_of(i_) * 262144; outp = At + (long)slot_of(d) * 262144; }
    else           { Xp = Au + (long)slot_of(i_) * 262144; Yp = At + (long)slot_of(m_) * 262144; outp = Au + (long)slot_of(d) * 262144; }

    int tid = threadIdx.x, w = tid >> 6, lane = tid & 63, q = lane >> 4, r = lane & 15;

    for (int i2 = tid; i2 < 64 * 64; i2 += 256) {
        int row = i2 >> 6, c8 = i2 & 63;
        ushort8 v = *(const ushort8*)(Xp + (long)(mb * 64 + row) * 512 + c8 * 8);
        *(ushort8*)&ldsX[row * 512 + ((c8 ^ (row & 7)) << 3)] = v;
    }
    __syncthreads();

    f32x4 acc[4][2];
    for (int a1 = 0; a1 < 4; a1++) for (int b1 = 0; b1 < 2; b1++) acc[a1][b1] = (f32x4){0.f, 0.f, 0.f, 0.f};

    int n0 = nb * 128 + w * 32;
    for (int kt = 0; kt < 16; kt++) {
        bf16x8 b0 = *(const bf16x8*)(Yp + (long)(n0 + r) * 512 + kt * 32 + q * 8);
        bf16x8 b1 = *(const bf16x8*)(Yp + (long)(n0 + 16 + r) * 512 + kt * 32 + q * 8);
        int g2 = kt * 4 + q;
#pragma unroll
        for (int mi = 0; mi < 4; mi++) {
            int row = mi * 16 + r;
            bf16x8 a = *(bf16x8*)&ldsX[row * 512 + ((g2 ^ (row & 7)) << 3)];
            acc[mi][0] = MFMA16(a, b0, acc[mi][0]);
            acc[mi][1] = MFMA16(a, b1, acc[mi][1]);
        }
    }
    for (int mi = 0; mi < 4; mi++) for (int nj = 0; nj < 2; nj++) {
        int m = mb * 64 + mi * 16 + q * 4, n = n0 + nj * 16 + r;
        for (int v = 0; v < 4; v++) outp[(long)(m + v) * 512 + n] = f2bf(acc[mi][nj][v]);
    }
}

// ---------------------------------------------------------------------------
// wk tile body: Wt[p] = (B.A^p)^T, p = 7-k8;  k8==7 -> copy B^T into Wt[0].
// ---------------------------------------------------------------------------
__device__ __forceinline__ void wk_tile(char* __restrict__ ws, ushort_t* ldsX,
                                        int k8, int mb) {
    ushort_t* At = (ushort_t*)(ws + OFF_AT);
    ushort_t* Bu = (ushort_t*)(ws + OFF_BU);
    ushort_t* Bt = (ushort_t*)(ws + OFF_BT);
    ushort_t* Wt = (ushort_t*)(ws + OFF_WT);

    int tid = threadIdx.x, w = tid >> 6, lane = tid & 63, q = lane >> 4, r = lane & 15;

    if (k8 == 7) {  // p = 0: Wt[0] = B^T
        for (int i2 = tid; i2 < 64 * 32; i2 += 256) {
            int row = i2 >> 5, c4 = i2 & 31;
            ushort4 v = *(const ushort4*)(Bt + (long)(mb * 64 + row) * 128 + c4 * 4);
            *(ushort4*)(Wt + (long)(mb * 64 + row) * 128 + c4 * 4) = v;
        }
        return;
    }

    int p = 7 - k8;
    const ushort_t* Xp = At + (long)slot_of(p) * 262144;
    for (int i2 = tid; i2 < 64 * 64; i2 += 256) {
        int row = i2 >> 6, c8 = i2 & 63;
        ushort8 v = *(const ushort8*)(Xp + (long)(mb * 64 + row) * 512 + c8 * 8);
        *(ushort8*)&ldsX[row * 512 + ((c8 ^ (row & 7)) << 3)] = v;
    }
    __syncthreads();

    f32x4 acc[4][2];
    for (int a1 = 0; a1 < 4; a1++) for (int b1 = 0; b1 < 2; b1++) acc[a1][b1] = (f32x4){0.f, 0.f, 0.f, 0.f};

    int n0 = w * 32;
    for (int kt = 0; kt < 16; kt++) {
        bf16x8 b0 = *(const bf16x8*)(Bu + (long)(n0 + r) * 512 + kt * 32 + q * 8);
        bf16x8 b1 = *(const bf16x8*)(Bu + (long)(n0 + 16 + r) * 512 + kt * 32 + q * 8);
        int g2 = kt * 4 + q;
#pragma unroll
        for (int mi = 0; mi < 4; mi++) {
            int row = mi * 16 + r;
            bf16x8 a = *(bf16x8*)&ldsX[row * 512 + ((g2 ^ (row & 7)) << 3)];
            acc[mi][0] = MFMA16(a, b0, acc[mi][0]);
            acc[mi][1] = MFMA16(a, b1, acc[mi][1]);
        }
    }
    ushort_t* Wp = Wt + (long)p * 65536;
    for (int mi = 0; mi < 4; mi++) for (int nj = 0; nj < 2; nj++) {
        int m = mb * 64 + mi * 16 + q * 4, n = n0 + nj * 16 + r;
        for (int v = 0; v < 4; v++) Wp[(long)(m + v) * 128 + n] = f2bf(acc[mi][nj][v]);
    }
}

// ---------------------------------------------------------------------------
// pow_stage: block-partitioned launch (grid 256):
//   [0, wkbase): pow tiles   [wkbase, ubase): wk tiles
//   [ubase, 256): riders -- umode 0: u-pack [ustart,uend); umode 1: B/x0/ident
// ---------------------------------------------------------------------------
__global__ __launch_bounds__(256) void pow_stage(char* __restrict__ ws,
                                                 const float* __restrict__ us,
                                                 const float* __restrict__ x0,
                                                 const float* __restrict__ B,
                                                 int4 dd, int4 mm, int4 ii,
                                                 int dual, int wkbase,
                                                 int ubase, int umode,
                                                 int ustart, int uend) {
    __shared__ ushort_t ldsX[64 * 512];
    int bx = blockIdx.x;

    if (ubase > 0 && bx >= ubase) {
        int tid = threadIdx.x;
        int nthr = (256 - ubase) * 256;
        if (umode == 0) {
            ushort_t* Z = (ushort_t*)(ws + OFF_Z);
            for (long gi = ustart + (long)(bx - ubase) * 256 + tid; gi < uend; gi += nthr) {
                int row = (int)(gi >> 7), g8 = (int)(gi & 127);
                int c = row >> 6, b = row & 63;
                const float* src = us + (long)b * 131072 + c * 1024 + g8 * 8;
                float4 v0 = *(const float4*)src;
                float4 v1 = *(const float4*)(src + 4);
                ushort8 h = { f2bf(v0.x), f2bf(v0.y), f2bf(v0.z), f2bf(v0.w),
                              f2bf(v1.x), f2bf(v1.y), f2bf(v1.z), f2bf(v1.w) };
                *(ushort8*)(Z + (long)row * 1536 + 512 + g8 * 8) = h;
            }
        } else {
            ushort_t* Bt  = (ushort_t*)(ws + OFF_BT);
            ushort_t* Bu  = (ushort_t*)(ws + OFF_BU);
            ushort_t* X0b = (ushort_t*)(ws + OFF_E2S);
            ushort_t* At1 = (ushort_t*)(ws + OFF_AT);
            for (long i = (long)(bx - ubase) * 256 + tid; i < 331776; i += nthr) {
                if (i < 65536) {
                    int kp = (int)(i >> 9), n = (int)(i & 511);
                    ushort_t v = f2bf(B[i]);
                    Bt[(long)n * 128 + kp] = v;
                    Bu[i] = v;
                } else if (i < 69632) {
                    long gi = i - 65536;
                    long e0 = gi * 8;
                    float4 v0 = *(const float4*)(x0 + e0);
                    float4 v1 = *(const float4*)(x0 + e0 + 4);
                    ushort8 h = { f2bf(v0.x), f2bf(v0.y), f2bf(v0.z), f2bf(v0.w),
                                  f2bf(v1.x), f2bf(v1.y), f2bf(v1.z), f2bf(v1.w) };
                    *(ushort8*)(X0b + e0) = h;
                } else {
                    long gi2 = i - 69632;
                    int n = (int)(gi2 >> 9), k2 = (int)(gi2 & 511);
                    At1[(long)16 * 262144 + gi2] = (n == k2) ? (ushort_t)0x3F80 : (ushort_t)0;
                }
            }
        }
        return;
    }
    if (wkbase > 0 && bx >= wkbase) {
        int widx = bx - wkbase;
        wk_tile(ws, ldsX, widx >> 3, widx & 7);
        return;
    }

    int nb = bx & 3, mb = (bx >> 2) & 7;
    int prod, pair;
    if (dual) { prod = (bx >> 5) & 1; pair = bx >> 6; }
    else      { prod = 0;             pair = bx >> 5; }
    int d = sel4(dd, pair), m_ = sel4(mm, pair), i_ = sel4(ii, pair);
    pow_tile(ws, ldsX, d, m_, i_, prod, mb, nb);
}

// ---------------------------------------------------------------------------
// e1g: E1[c] = Zu-chunk [64 x 1024] .NT Wstack -> E1slab[c]
// grid 512: c = bx>>2, nt = bx&3.  64m x 128n, 16 K-steps, stage-both.
// ---------------------------------------------------------------------------
__global__ __launch_bounds__(256, 4) void e1g(char* __restrict__ ws) {
    __shared__ ushort_t Alds[64 * 64];
    __shared__ ushort_t Blds[128 * 64];
    const ushort_t* Z  = (const ushort_t*)(ws + OFF_Z);
    const ushort_t* Wt = (const ushort_t*)(ws + OFF_WT);
    ushort_t* E1s = (ushort_t*)(ws + OFF_E1S);

    int bx = blockIdx.x;
    int c = bx >> 2, nt = bx & 3;
    int tid = threadIdx.x, w = tid >> 6, lane = tid & 63, q = lane >> 4, r = lane & 15;
    int wr = w >> 1, wc = w & 1;
    int l8 = lane >> 3, srcg = (lane & 7) ^ l8;

    const ushort_t* Xb = Z + (long)c * 64 * 1536 + 512;   // pitch 1536

    f32x4 acc[2][4];
#pragma unroll
    for (int a1 = 0; a1 < 2; a1++)
#pragma unroll
        for (int b1 = 0; b1 < 4; b1++) acc[a1][b1] = (f32x4){0.f, 0.f, 0.f, 0.f};

    for (int s = 0; s < 16; s++) {
        int k0 = s * 64;
#pragma unroll
        for (int i = 0; i < 2; i++) {
            int row = i * 32 + w * 8 + l8;
            gll16(Xb + (long)row * 1536 + k0 + srcg * 8, &Alds[i * 2048 + w * 512]);
        }
        const ushort_t* Yb = Wt + (long)(7 - (s >> 1)) * 65536 + (s & 1) * 64;
#pragma unroll
        for (int i = 0; i < 4; i++) {
            int row = i * 32 + w * 8 + l8;
            gll16(Yb + (long)(nt * 128 + row) * 128 + srcg * 8, &Blds[i * 2048 + w * 512]);
        }
        __syncthreads();
#pragma unroll
        for (int kt = 0; kt < 2; kt++) {
            int g2 = kt * 4 + q;
            bf16x8 a[2], b[4];
#pragma unroll
            for (int mi = 0; mi < 2; mi++) {
                int row = wr * 32 + mi * 16 + r;
                a[mi] = *(bf16x8*)&Alds[row * 64 + ((g2 ^ (row & 7)) << 3)];
            }
#pragma unroll
            for (int nj = 0; nj < 4; nj++) {
                int row = wc * 64 + nj * 16 + r;
                b[nj] = *(bf16x8*)&Blds[row * 64 + ((g2 ^ (row & 7)) << 3)];
            }
#pragma unroll
            for (int mi = 0; mi < 2; mi++)
#pragma unroll
                for (int nj = 0; nj < 4; nj++)
                    acc[mi][nj] = MFMA16(a[mi], b[nj], acc[mi][nj]);
        }
        __syncthreads();
    }

#pragma unroll
    for (int mi = 0; mi < 2; mi++)
#pragma unroll
        for (int nj = 0; nj < 4; nj++) {
            int m = wr * 32 + mi * 16 + q * 4;
            int n = nt * 128 + wc * 64 + nj * 16 + r;
#pragma unroll
            for (int v = 0; v < 4; v++)
                E1s[(long)c * 32768 + (long)(m + v) * 512 + n] = f2bf(acc[mi][nj][v]);
        }
}

// ---------------------------------------------------------------------------
// e2g: E2[g] = sum_{t=0..7} E1[8g+t].A^{8(7-t)} -> E2slab[1+g]  (t=7 -> I)
// grid 512: g = bx>>5, mb = (bx>>4)&1, ntb = bx&15.  32m x 32n, 64 K-steps.
// ---------------------------------------------------------------------------
__global__ __launch_bounds__(256, 4) void e2g(char* __restrict__ ws) {
    __shared__ ushort_t Alds[32 * 64];
    __shared__ ushort_t Blds[32 * 64];
    const ushort_t* At  = (const ushort_t*)(ws + OFF_AT);
    const ushort_t* E1s = (const ushort_t*)(ws + OFF_E1S);
    ushort_t* E2s = (ushort_t*)(ws + OFF_E2S);

    int bx = blockIdx.x;
    int g = bx >> 5, mb = (bx >> 4) & 1, ntb = bx & 15;
    int tid = threadIdx.x, w = tid >> 6, lane = tid & 63, q = lane >> 4, r = lane & 15;
    int wr = w >> 1, wc = w & 1;
    int l8 = lane >> 3, srcg = (lane & 7) ^ l8;

    f32x4 acc = (f32x4){0.f, 0.f, 0.f, 0.f};

    for (int s = 0; s < 64; s++) {
        int t = s >> 3, k0 = (s & 7) * 64;
        const ushort_t* Xp = E1s + (long)(8 * g + t) * 32768 + (long)mb * 32 * 512;
        const ushort_t* Yb = At + (long)slot_of(8 * (7 - t)) * 262144;
        {
            int row = w * 8 + l8;   // 0..31
            gll16(Xp + (long)row * 512 + k0 + srcg * 8, &Alds[w * 512]);
            gll16(Yb + (long)(ntb * 32 + row) * 512 + k0 + srcg * 8, &Blds[w * 512]);
        }
        __syncthreads();
#pragma unroll
        for (int kt = 0; kt < 2; kt++) {
            int g2 = kt * 4 + q;
            int arow = wr * 16 + r;
            bf16x8 a = *(bf16x8*)&Alds[arow * 64 + ((g2 ^ (arow & 7)) << 3)];
            int brow = wc * 16 + r;
            bf16x8 b = *(bf16x8*)&Blds[brow * 64 + ((g2 ^ (brow & 7)) << 3)];
            acc = MFMA16(a, b, acc);
        }
        __syncthreads();
    }

    {
        int m = mb * 32 + wr * 16 + q * 4;
        int n = ntb * 32 + wc * 16 + r;
#pragma unroll
        for (int v = 0; v < 4; v++)
            E2s[(long)(1 + g) * 32768 + (long)(m + v) * 512 + n] = f2bf(acc[v]);
    }
}

// ---------------------------------------------------------------------------
// s1x: S1[c'] = E2slab[g].A^{8j} + [j==0 && g>=1] E2slab[g-1].A^64
//             + sum_{t<j} E1[8g+t].A^{8(j-1-t)}      (c' = 8g+j)
// c' in 0..128 (c'=128: g=16,j=0 -> E2[15] + E2[14].A^64).
// Writes: Z state cols (c'<=127, bf16) AND dout[t=8c'-1] (c'>=1, fp32).
// grid 516.  j-BALANCED mapping for c'<128.
// ---------------------------------------------------------------------------
__global__ __launch_bounds__(256, 4) void s1x(float* __restrict__ dout,
                                              char* __restrict__ ws) {
    __shared__ ushort_t Alds[64 * 64];
    __shared__ ushort_t Blds[128 * 64];
    const ushort_t* At  = (const ushort_t*)(ws + OFF_AT);
    const ushort_t* E1s = (const ushort_t*)(ws + OFF_E1S);
    const ushort_t* E2s = (const ushort_t*)(ws + OFF_E2S);
    ushort_t* Z = (ushort_t*)(ws + OFF_Z);

    int bx = blockIdx.x;
    int t0 = bx >> 2, nt = bx & 3;
    int g, j;
    if (t0 == 128) { g = 16; j = 0; }
    else {
        g = t0 >> 3;
        int jj = t0 & 7;
        j = (g >= 8) ? (7 - jj) : jj;    // balance heavy/light across CUs
    }
    int c = g * 8 + j;
    int extra = (j == 0 && g >= 1) ? 1 : 0;
    int nterms = 1 + extra + j;
    int S = nterms * 8;
    int tid = threadIdx.x, w = tid >> 6, lane = tid & 63, q = lane >> 4, r = lane & 15;
    int wr = w >> 1, wc = w & 1;
    int l8 = lane >> 3, srcg = (lane & 7) ^ l8;

    auto xptr = [&](int t) -> const ushort_t* {
        if (t == 0) return E2s + (long)g * 32768;
        if (extra && t == 1) return E2s + (long)(g - 1) * 32768;
        return E1s + (long)(8 * g + t - 1 - extra) * 32768;
    };
    auto yptr = [&](int t) -> const ushort_t* {
        int p = (t == 0) ? 8 * j : ((extra && t == 1) ? 64 : 8 * (j - t + extra));
        return At + (long)slot_of(p) * 262144;
    };

    f32x4 acc[2][4];
#pragma unroll
    for (int a1 = 0; a1 < 2; a1++)
#pragma unroll
        for (int b1 = 0; b1 < 4; b1++) acc[a1][b1] = (f32x4){0.f, 0.f, 0.f, 0.f};

    for (int s = 0; s < S; s++) {
        int t = s >> 3, k0 = (s & 7) * 64;
        const ushort_t* Xp = xptr(t);
        const ushort_t* Yb = yptr(t);
#pragma unroll
        for (int i = 0; i < 2; i++) {
            int row = i * 32 + w * 8 + l8;
            gll16(Xp + (long)row * 512 + k0 + srcg * 8, &Alds[i * 2048 + w * 512]);
        }
#pragma unroll
        for (int i = 0; i < 4; i++) {
            int row = i * 32 + w * 8 + l8;
            gll16(Yb + (long)(nt * 128 + row) * 512 + k0 + srcg * 8, &Blds[i * 2048 + w * 512]);
        }
        __syncthreads();
#pragma unroll
        for (int kt = 0; kt < 2; kt++) {
            int g2 = kt * 4 + q;
            bf16x8 a[2], b[4];
#pragma unroll
            for (int mi = 0; mi < 2; mi++) {
                int row = wr * 32 + mi * 16 + r;
                a[mi] = *(bf16x8*)&Alds[row * 64 + ((g2 ^ (row & 7)) << 3)];
            }
#pragma unroll
            for (int nj = 0; nj < 4; nj++) {
                int row = wc * 64 + nj * 16 + r;
                b[nj] = *(bf16x8*)&Blds[row * 64 + ((g2 ^ (row & 7)) << 3)];
            }
#pragma unroll
            for (int mi = 0; mi < 2; mi++)
#pragma unroll
                for (int nj = 0; nj < 4; nj++)
                    acc[mi][nj] = MFMA16(a[mi], b[nj], acc[mi][nj]);
        }
        __syncthreads();
    }

#pragma unroll
    for (int mi = 0; mi < 2; mi++)
#pragma unroll
        for (int nj = 0; nj < 4; nj++) {
            int m = wr * 32 + mi * 16 + q * 4;
            int n = nt * 128 + wc * 64 + nj * 16 + r;
#pragma unroll
            for (int v = 0; v < 4; v++) {
                float val = acc[mi][nj][v];
                int row = m + v;
                if (c < 128)
                    Z[(long)(c * 64 + row) * 1536 + n] = f2bf(val);
                if (c >= 1)
                    dout[(long)row * 524288 + (long)(8 * c - 1) * 512 + n] = val;
            }
        }
}

// ---------------------------------------------------------------------------
// outg: out = Z[:, :K_k] . [At[k+1] | Wt]^T for k=0..6 (k=7 done by s1x).
// grid 1792: nt = bx/448, rem = bx%448, k = 6-(rem>>6) [heavy first],
// mt = rem&63.  128x128, stage-both.
// ---------------------------------------------------------------------------
__global__ __launch_bounds__(256, 4) void outg(float* __restrict__ dout,
                                               char* __restrict__ ws) {
    __shared__ ushort_t Alds[128 * 64];
    __shared__ ushort_t Blds[128 * 64];
    const ushort_t* Z  = (const ushort_t*)(ws + OFF_Z);
    const ushort_t* At = (const ushort_t*)(ws + OFF_AT);
    const ushort_t* Wt = (const ushort_t*)(ws + OFF_WT);

    int bx = blockIdx.x;
    int nt = bx / 448;
    int rem = bx - nt * 448;
    int k = 6 - (rem >> 6);      // heavy k first -> light tail
    int mt = rem & 63;
    int tid = threadIdx.x, w = tid >> 6, lane = tid & 63, q = lane >> 4, r = lane & 15;
    int wr = w >> 1, wc = w & 1;
    int l8 = lane >> 3, srcg = (lane & 7) ^ l8;

    const ushort_t* Xb = Z + (long)mt * 128 * 1536;
    const ushort_t* Ya = At + (long)slot_of(k + 1) * 262144;
    int Ks = 8 + 2 * (k + 1);

    f32x4 acc[4][4];
#pragma unroll
    for (int a1 = 0; a1 < 4; a1++)
#pragma unroll
        for (int b1 = 0; b1 < 4; b1++) acc[a1][b1] = (f32x4){0.f, 0.f, 0.f, 0.f};

    for (int s = 0; s < Ks; s++) {
        int k0 = s * 64;
#pragma unroll
        for (int i = 0; i < 4; i++) {
            int row = i * 32 + w * 8 + l8;
            gll16(Xb + (long)row * 1536 + k0 + srcg * 8, &Alds[i * 2048 + w * 512]);
        }
        if (k0 < 512) {
#pragma unroll
            for (int i = 0; i < 4; i++) {
                int row = i * 32 + w * 8 + l8;
                gll16(Ya + (long)(nt * 128 + row) * 512 + k0 + srcg * 8, &Blds[i * 2048 + w * 512]);
            }
        } else {
            int uc = k0 - 512;
            const ushort_t* Yb = Wt + (long)(k - (uc >> 7)) * 65536 + (uc & 127);
#pragma unroll
            for (int i = 0; i < 4; i++) {
                int row = i * 32 + w * 8 + l8;
                gll16(Yb + (long)(nt * 128 + row) * 128 + srcg * 8, &Blds[i * 2048 + w * 512]);
            }
        }
        __syncthreads();
#pragma unroll
        for (int kt = 0; kt < 2; kt++) {
            int g2 = kt * 4 + q;
            bf16x8 a[4], b[4];
#pragma unroll
            for (int mi = 0; mi < 4; mi++) {
                int row = wr * 64 + mi * 16 + r;
                a[mi] = *(bf16x8*)&Alds[row * 64 + ((g2 ^ (row & 7)) << 3)];
            }
#pragma unroll
            for (int nj = 0; nj < 4; nj++) {
                int row = wc * 64 + nj * 16 + r;
                b[nj] = *(bf16x8*)&Blds[row * 64 + ((g2 ^ (row & 7)) << 3)];
            }
#pragma unroll
            for (int mi = 0; mi < 4; mi++)
#pragma unroll
                for (int nj = 0; nj < 4; nj++)
                    acc[mi][nj] = MFMA16(a[mi], b[nj], acc[mi][nj]);
        }
        __syncthreads();
    }

#pragma unroll
    for (int mi = 0; mi < 4; mi++) {
        int m = mt * 128 + wr * 64 + mi * 16 + q * 4;
#pragma unroll
        for (int nj = 0; nj < 4; nj++) {
            int n = nt * 128 + wc * 64 + nj * 16 + r;
#pragma unroll
            for (int v = 0; v < 4; v++) {
                int mm = m + v;
                dout[(long)(mm & 63) * 524288 + (long)(((mm >> 6) << 3) + k) * 512 + n] = acc[mi][nj][v];
            }
        }
    }
}

// ---------------------------------------------------------------------------
extern "C" void kernel_launch(void* const* d_in, const int* in_sizes, int n_in,
                              void* d_out, int out_size, void* d_ws, size_t ws_size,
                              hipStream_t stream) {
    const float* x0 = (const float*)d_in[0];
    const float* us = (const float*)d_in[1];
    const float* A  = (const float*)d_in[2];
    const float* B  = (const float*)d_in[3];
    float* dout = (float*)d_out;
    char* ws = (char*)d_ws;

    prep_kernel<<<2048, 256, 0, stream>>>(A, ws);

    // power ladder, grid 256 each stage:
    //   stage 0 riders: B/x0/identity (umode 1)
    //   stage 3 carries wk (blocks 64..127); u-pack rides stages 1,3,4,5
    const int stdual[6]  = {1, 1, 1, 1, 1, 0};
    const int stwk[6]    = {0, 0, 0, 64, 0, 0};
    const int stub[6]    = {64, 128, 0, 128, 128, 128};    // ubase (0 = none)
    const int stum[6]    = {1, 0, 0, 0, 0, 0};             // umode
    const int stus[6]    = {0, 0, 0, 262144, 524288, 786432};
    const int stue[6]    = {0, 262144, 0, 524288, 786432, 1048576};
    const int stpw[6]    = {64, 128, 256, 64, 128, 128};
    const int std_[6][4] = {{2,0,0,0},{3,4,0,0},{5,6,7,8},{16,0,0,0},{24,32,0,0},{40,48,56,64}};
    const int stm[6][4]  = {{1,0,0,0},{2,2,0,0},{4,4,4,4},{8,0,0,0},{16,16,0,0},{32,32,32,32}};
    const int sti[6][4]  = {{1,0,0,0},{1,2,0,0},{1,2,3,4},{8,0,0,0},{8,16,0,0},{8,16,24,32}};
    for (int s = 0; s < 6; s++) {
        int4 dd = {std_[s][0], std_[s][1], std_[s][2], std_[s][3]};
        int4 mm = {stm[s][0], stm[s][1], stm[s][2], stm[s][3]};
        int4 ii = {sti[s][0], sti[s][1], sti[s][2], sti[s][3]};
        int blocks = (stub[s] > 0) ? 256 : stpw[s] + stwk[s];
        pow_stage<<<blocks, 256, 0, stream>>>(ws, us, x0, B, dd, mm, ii,
                                              stdual[s], stwk[s], stub[s],
                                              stum[s], stus[s], stue[s]);
    }

    e1g<<<512, 256, 0, stream>>>(ws);           // E1 -> E1slab
    e2g<<<512, 256, 0, stream>>>(ws);           // E2 -> E2slab[1+g]
    s1x<<<516, 256, 0, stream>>>(dout, ws);     // S1 -> Z state + dout k=7 slices
    outg<<<1792, 256, 0, stream>>>(dout, ws);   // outputs k=0..6
}

// Round 18
// 243.423 us; speedup vs baseline: 1.1637x; 1.0139x over previous
//
#include <hip/hip_runtime.h>

// ---------------------------------------------------------------------------
// LinearSSM: x_{t+1} = x_t @ A + u_t @ B   (batch=64, T=1024, n=512, p=128)
// Fully parallel chunked solve.  All heavy GEMMs: proven 2-barrier structure,
// global_load_lds 16B into XOR-swizzled LDS, __launch_bounds__(256,4).
//   prep: bf16 casts of A only (2048 blocks)
//   pow stages (grid 256 each): A^2..A^64 dual chains; wk rides stage 3;
//     B/x0/identity ride stage 0; u-pack rides stages 1,3,4,5
//   e1g: E1[c] = u-chunk . Wstack -> E1slab   (512 blocks, 64x128, K=1024)
//   e2g: E2[g] = sum_t E1[8g+t].A^{8(7-t)}    (512 blocks, 32x32, K=4096)
//   s1x: S1[c'] c'=0..128 -> Z state cols (c'<=127) AND dout[t=8c'-1]
//   outg (k=0..3): out[t=8c+k] = S1[c].A^{k+1} + sum_{j<=k} u_j.(B.A^{k-j});
//     k=3 blocks also write mid-state M[c]=x_{8c+4} (bf16) into E1S region
//     (dead after s1x).  -21.4% outg FLOPs via the 2-level split.
//   outg2 (k=4..6): out[t=8c+k] = M[c].A^{k-3} + sum_{j=4..k} u_j.(B.A^{k-j})
// ---------------------------------------------------------------------------

typedef __attribute__((ext_vector_type(8))) short bf16x8;
typedef __attribute__((ext_vector_type(8))) unsigned short ushort8;
typedef __attribute__((ext_vector_type(4))) float f32x4;
typedef unsigned short ushort_t;

#define MFMA16(a, b, c) __builtin_amdgcn_mfma_f32_16x16x32_bf16(a, b, c, 0, 0, 0)

// workspace layout (bytes)
#define OFF_AT  0UL           // 17 slots (A^p)^T bf16 [512][512]; slot16 = I
#define OFF_AU  8912896UL     // 12 slots A^p bf16 [512][512]
#define OFF_BT  15204352UL    // B^T bf16 [512][128]
#define OFF_BU  15335424UL    // B   bf16 [128][512]
#define OFF_WT  15466496UL    // 8 x (B.A^p)^T bf16 [512][128]
#define OFF_Z   16515072UL    // [8192][1536] bf16: [S1 | u-chunk]
#define OFF_E1S 41680896UL    // [128][64][512] bf16 : E1 slab; reused as M[8192][512]
#define OFF_E2S 50069504UL    // [17][64][512] bf16  : slot0 = x0, 1+g = E2[g]

__host__ __device__ __forceinline__ int slot_of(int p) {
    if (p == 0) return 16;          // identity
    if (p <= 8) return p - 1;
    return 7 + (p >> 3);            // 16,24,..,64 -> 9..15
}

__device__ __forceinline__ unsigned short f2bf(float f) {
    union { float f; unsigned u; } v; v.f = f;
    unsigned r = v.u + 0x7FFFu + ((v.u >> 16) & 1u);
    return (unsigned short)(r >> 16);
}

__device__ __forceinline__ int sel4(int4 v, int p) {
    return p == 0 ? v.x : p == 1 ? v.y : p == 2 ? v.z : v.w;
}

typedef __attribute__((address_space(3))) unsigned int as3_u32;
typedef __attribute__((address_space(1))) const unsigned int as1_u32;
__device__ __forceinline__ void gll16(const void* g, void* l) {
    __builtin_amdgcn_global_load_lds((as1_u32*)g, (as3_u32*)l, 16, 0, 0);
}

// ---------------------------------------------------------------------------
// prep: bf16 casts of A only.  524288 items, grid 2048.
// ---------------------------------------------------------------------------
__global__ __launch_bounds__(256) void prep_kernel(const float* __restrict__ A,
                                                   char* __restrict__ ws) {
    ushort_t* At1 = (ushort_t*)(ws + OFF_AT);
    ushort_t* Au1 = (ushort_t*)(ws + OFF_AU);
    long idx = (long)blockIdx.x * 256 + threadIdx.x;
    if (idx < 262144) {
        Au1[idx] = f2bf(A[idx]);                          // coalesced r/w
    } else {
        long gi = idx - 262144;
        int n = (int)(gi >> 9), k = (int)(gi & 511);
        At1[gi] = f2bf(A[(long)k * 512 + n]);             // scattered read, coal. write
    }
}

// ---------------------------------------------------------------------------
// pow tile body: At[d] = At[m] .NT Au[i] (prod 0); Au[d] = Au[i] .NT At[m] (1)
// ---------------------------------------------------------------------------
__device__ __forceinline__ void pow_tile(char* __restrict__ ws, ushort_t* ldsX,
                                         int d, int m_, int i_, int prod,
                                         int mb, int nb) {
    ushort_t* At = (ushort_t*)(ws + OFF_AT);
    ushort_t* Au = (ushort_t*)(ws + OFF_AU);
    const ushort_t *Xp, *Yp; ushort_t* outp;
    if (prod == 0) { Xp = At + (long)slot_of(m_) * 262144; Yp = Au + (long)slot_of(i_) * 262144; outp = At + (long)slot_of(d) * 262144; }
    else           { Xp = Au + (long)slot_of(i_) * 262144; Yp = At + (long)slot_of(m_) * 262144; outp = Au + (long)slot_of(d) * 262144; }

    int tid = threadIdx.x, w = tid >> 6, lane = tid & 63, q = lane >> 4, r = lane & 15;

    for (int i2 = tid; i2 < 64 * 64; i2 += 256) {
        int row = i2 >> 6, c8 = i2 & 63;
        ushort8 v = *(const ushort8*)(Xp + (long)(mb * 64 + row) * 512 + c8 * 8);
        *(ushort8*)&ldsX[row * 512 + ((c8 ^ (row & 7)) << 3)] = v;
    }
    __syncthreads();

    f32x4 acc[4][2];
    for (int a1 = 0; a1 < 4; a1++) for (int b1 = 0; b1 < 2; b1++) acc[a1][b1] = (f32x4){0.f, 0.f, 0.f, 0.f};

    int n0 = nb * 128 + w * 32;
    for (int kt = 0; kt < 16; kt++) {
        bf16x8 b0 = *(const bf16x8*)(Yp + (long)(n0 + r) * 512 + kt * 32 + q * 8);
        bf16x8 b1 = *(const bf16x8*)(Yp + (long)(n0 + 16 + r) * 512 + kt * 32 + q * 8);
        int g2 = kt * 4 + q;
#pragma unroll
        for (int mi = 0; mi < 4; mi++) {
            int row = mi * 16 + r;
            bf16x8 a = *(bf16x8*)&ldsX[row * 512 + ((g2 ^ (row & 7)) << 3)];
            acc[mi][0] = MFMA16(a, b0, acc[mi][0]);
            acc[mi][1] = MFMA16(a, b1, acc[mi][1]);
        }
    }
    for (int mi = 0; mi < 4; mi++) for (int nj = 0; nj < 2; nj++) {
        int m = mb * 64 + mi * 16 + q * 4, n = n0 + nj * 16 + r;
        for (int v = 0; v < 4; v++) outp[(long)(m + v) * 512 + n] = f2bf(acc[mi][nj][v]);
    }
}

// ---------------------------------------------------------------------------
// wk tile body: Wt[p] = (B.A^p)^T, p = 7-k8;  k8==7 -> copy B^T into Wt[0].
// ---------------------------------------------------------------------------
__device__ __forceinline__ void wk_tile(char* __restrict__ ws, ushort_t* ldsX,
                                        int k8, int mb) {
    ushort_t* At = (ushort_t*)(ws + OFF_AT);
    ushort_t* Bu = (ushort_t*)(ws + OFF_BU);
    ushort_t* Bt = (ushort_t*)(ws + OFF_BT);
    ushort_t* Wt = (ushort_t*)(ws + OFF_WT);

    int tid = threadIdx.x, w = tid >> 6, lane = tid & 63, q = lane >> 4, r = lane & 15;

    if (k8 == 7) {  // p = 0: Wt[0] = B^T
        for (int i2 = tid; i2 < 64 * 32; i2 += 256) {
            int row = i2 >> 5, c4 = i2 & 31;
            ushort4 v = *(const ushort4*)(Bt + (long)(mb * 64 + row) * 128 + c4 * 4);
            *(ushort4*)(Wt + (long)(mb * 64 + row) * 128 + c4 * 4) = v;
        }
        return;
    }

    int p = 7 - k8;
    const ushort_t* Xp = At + (long)slot_of(p) * 262144;
    for (int i2 = tid; i2 < 64 * 64; i2 += 256) {
        int row = i2 >> 6, c8 = i2 & 63;
        ushort8 v = *(const ushort8*)(Xp + (long)(mb * 64 + row) * 512 + c8 * 8);
        *(ushort8*)&ldsX[row * 512 + ((c8 ^ (row & 7)) << 3)] = v;
    }
    __syncthreads();

    f32x4 acc[4][2];
    for (int a1 = 0; a1 < 4; a1++) for (int b1 = 0; b1 < 2; b1++) acc[a1][b1] = (f32x4){0.f, 0.f, 0.f, 0.f};

    int n0 = w * 32;
    for (int kt = 0; kt < 16; kt++) {
        bf16x8 b0 = *(const bf16x8*)(Bu + (long)(n0 + r) * 512 + kt * 32 + q * 8);
        bf16x8 b1 = *(const bf16x8*)(Bu + (long)(n0 + 16 + r) * 512 + kt * 32 + q * 8);
        int g2 = kt * 4 + q;
#pragma unroll
        for (int mi = 0; mi < 4; mi++) {
            int row = mi * 16 + r;
            bf16x8 a = *(bf16x8*)&ldsX[row * 512 + ((g2 ^ (row & 7)) << 3)];
            acc[mi][0] = MFMA16(a, b0, acc[mi][0]);
            acc[mi][1] = MFMA16(a, b1, acc[mi][1]);
        }
    }
    ushort_t* Wp = Wt + (long)p * 65536;
    for (int mi = 0; mi < 4; mi++) for (int nj = 0; nj < 2; nj++) {
        int m = mb * 64 + mi * 16 + q * 4, n = n0 + nj * 16 + r;
        for (int v = 0; v < 4; v++) Wp[(long)(m + v) * 128 + n] = f2bf(acc[mi][nj][v]);
    }
}

// ---------------------------------------------------------------------------
// pow_stage: block-partitioned launch (grid 256):
//   [0, wkbase): pow tiles   [wkbase, ubase): wk tiles
//   [ubase, 256): riders -- umode 0: u-pack [ustart,uend); umode 1: B/x0/ident
// ---------------------------------------------------------------------------
__global__ __launch_bounds__(256) void pow_stage(char* __restrict__ ws,
                                                 const float* __restrict__ us,
                                                 const float* __restrict__ x0,
                                                 const float* __restrict__ B,
                                                 int4 dd, int4 mm, int4 ii,
                                                 int dual, int wkbase,
                                                 int ubase, int umode,
                                                 int ustart, int uend) {
    __shared__ ushort_t ldsX[64 * 512];
    int bx = blockIdx.x;

    if (ubase > 0 && bx >= ubase) {
        int tid = threadIdx.x;
        int nthr = (256 - ubase) * 256;
        if (umode == 0) {
            ushort_t* Z = (ushort_t*)(ws + OFF_Z);
            for (long gi = ustart + (long)(bx - ubase) * 256 + tid; gi < uend; gi += nthr) {
                int row = (int)(gi >> 7), g8 = (int)(gi & 127);
                int c = row >> 6, b = row & 63;
                const float* src = us + (long)b * 131072 + c * 1024 + g8 * 8;
                float4 v0 = *(const float4*)src;
                float4 v1 = *(const float4*)(src + 4);
                ushort8 h = { f2bf(v0.x), f2bf(v0.y), f2bf(v0.z), f2bf(v0.w),
                              f2bf(v1.x), f2bf(v1.y), f2bf(v1.z), f2bf(v1.w) };
                *(ushort8*)(Z + (long)row * 1536 + 512 + g8 * 8) = h;
            }
        } else {
            ushort_t* Bt  = (ushort_t*)(ws + OFF_BT);
            ushort_t* Bu  = (ushort_t*)(ws + OFF_BU);
            ushort_t* X0b = (ushort_t*)(ws + OFF_E2S);
            ushort_t* At1 = (ushort_t*)(ws + OFF_AT);
            for (long i = (long)(bx - ubase) * 256 + tid; i < 331776; i += nthr) {
                if (i < 65536) {
                    int kp = (int)(i >> 9), n = (int)(i & 511);
                    ushort_t v = f2bf(B[i]);
                    Bt[(long)n * 128 + kp] = v;
                    Bu[i] = v;
                } else if (i < 69632) {
                    long gi = i - 65536;
                    long e0 = gi * 8;
                    float4 v0 = *(const float4*)(x0 + e0);
                    float4 v1 = *(const float4*)(x0 + e0 + 4);
                    ushort8 h = { f2bf(v0.x), f2bf(v0.y), f2bf(v0.z), f2bf(v0.w),
                                  f2bf(v1.x), f2bf(v1.y), f2bf(v1.z), f2bf(v1.w) };
                    *(ushort8*)(X0b + e0) = h;
                } else {
                    long gi2 = i - 69632;
                    int n = (int)(gi2 >> 9), k2 = (int)(gi2 & 511);
                    At1[(long)16 * 262144 + gi2] = (n == k2) ? (ushort_t)0x3F80 : (ushort_t)0;
                }
            }
        }
        return;
    }
    if (wkbase > 0 && bx >= wkbase) {
        int widx = bx - wkbase;
        wk_tile(ws, ldsX, widx >> 3, widx & 7);
        return;
    }

    int nb = bx & 3, mb = (bx >> 2) & 7;
    int prod, pair;
    if (dual) { prod = (bx >> 5) & 1; pair = bx >> 6; }
    else      { prod = 0;             pair = bx >> 5; }
    int d = sel4(dd, pair), m_ = sel4(mm, pair), i_ = sel4(ii, pair);
    pow_tile(ws, ldsX, d, m_, i_, prod, mb, nb);
}

// ---------------------------------------------------------------------------
// e1g: E1[c] = Zu-chunk [64 x 1024] .NT Wstack -> E1slab[c]
// grid 512: c = bx>>2, nt = bx&3.  64m x 128n, 16 K-steps, stage-both.
// ---------------------------------------------------------------------------
__global__ __launch_bounds__(256, 4) void e1g(char* __restrict__ ws) {
    __shared__ ushort_t Alds[64 * 64];
    __shared__ ushort_t Blds[128 * 64];
    const ushort_t* Z  = (const ushort_t*)(ws + OFF_Z);
    const ushort_t* Wt = (const ushort_t*)(ws + OFF_WT);
    ushort_t* E1s = (ushort_t*)(ws + OFF_E1S);

    int bx = blockIdx.x;
    int c = bx >> 2, nt = bx & 3;
    int tid = threadIdx.x, w = tid >> 6, lane = tid & 63, q = lane >> 4, r = lane & 15;
    int wr = w >> 1, wc = w & 1;
    int l8 = lane >> 3, srcg = (lane & 7) ^ l8;

    const ushort_t* Xb = Z + (long)c * 64 * 1536 + 512;   // pitch 1536

    f32x4 acc[2][4];
#pragma unroll
    for (int a1 = 0; a1 < 2; a1++)
#pragma unroll
        for (int b1 = 0; b1 < 4; b1++) acc[a1][b1] = (f32x4){0.f, 0.f, 0.f, 0.f};

    for (int s = 0; s < 16; s++) {
        int k0 = s * 64;
#pragma unroll
        for (int i = 0; i < 2; i++) {
            int row = i * 32 + w * 8 + l8;
            gll16(Xb + (long)row * 1536 + k0 + srcg * 8, &Alds[i * 2048 + w * 512]);
        }
        const ushort_t* Yb = Wt + (long)(7 - (s >> 1)) * 65536 + (s & 1) * 64;
#pragma unroll
        for (int i = 0; i < 4; i++) {
            int row = i * 32 + w * 8 + l8;
            gll16(Yb + (long)(nt * 128 + row) * 128 + srcg * 8, &Blds[i * 2048 + w * 512]);
        }
        __syncthreads();
#pragma unroll
        for (int kt = 0; kt < 2; kt++) {
            int g2 = kt * 4 + q;
            bf16x8 a[2], b[4];
#pragma unroll
            for (int mi = 0; mi < 2; mi++) {
                int row = wr * 32 + mi * 16 + r;
                a[mi] = *(bf16x8*)&Alds[row * 64 + ((g2 ^ (row & 7)) << 3)];
            }
#pragma unroll
            for (int nj = 0; nj < 4; nj++) {
                int row = wc * 64 + nj * 16 + r;
                b[nj] = *(bf16x8*)&Blds[row * 64 + ((g2 ^ (row & 7)) << 3)];
            }
#pragma unroll
            for (int mi = 0; mi < 2; mi++)
#pragma unroll
                for (int nj = 0; nj < 4; nj++)
                    acc[mi][nj] = MFMA16(a[mi], b[nj], acc[mi][nj]);
        }
        __syncthreads();
    }

#pragma unroll
    for (int mi = 0; mi < 2; mi++)
#pragma unroll
        for (int nj = 0; nj < 4; nj++) {
            int m = wr * 32 + mi * 16 + q * 4;
            int n = nt * 128 + wc * 64 + nj * 16 + r;
#pragma unroll
            for (int v = 0; v < 4; v++)
                E1s[(long)c * 32768 + (long)(m + v) * 512 + n] = f2bf(acc[mi][nj][v]);
        }
}

// ---------------------------------------------------------------------------
// e2g: E2[g] = sum_{t=0..7} E1[8g+t].A^{8(7-t)} -> E2slab[1+g]  (t=7 -> I)
// grid 512: g = bx>>5, mb = (bx>>4)&1, ntb = bx&15.  32m x 32n, 64 K-steps.
// ---------------------------------------------------------------------------
__global__ __launch_bounds__(256, 4) void e2g(char* __restrict__ ws) {
    __shared__ ushort_t Alds[32 * 64];
    __shared__ ushort_t Blds[32 * 64];
    const ushort_t* At  = (const ushort_t*)(ws + OFF_AT);
    const ushort_t* E1s = (const ushort_t*)(ws + OFF_E1S);
    ushort_t* E2s = (ushort_t*)(ws + OFF_E2S);

    int bx = blockIdx.x;
    int g = bx >> 5, mb = (bx >> 4) & 1, ntb = bx & 15;
    int tid = threadIdx.x, w = tid >> 6, lane = tid & 63, q = lane >> 4, r = lane & 15;
    int wr = w >> 1, wc = w & 1;
    int l8 = lane >> 3, srcg = (lane & 7) ^ l8;

    f32x4 acc = (f32x4){0.f, 0.f, 0.f, 0.f};

    for (int s = 0; s < 64; s++) {
        int t = s >> 3, k0 = (s & 7) * 64;
        const ushort_t* Xp = E1s + (long)(8 * g + t) * 32768 + (long)mb * 32 * 512;
        const ushort_t* Yb = At + (long)slot_of(8 * (7 - t)) * 262144;
        {
            int row = w * 8 + l8;   // 0..31
            gll16(Xp + (long)row * 512 + k0 + srcg * 8, &Alds[w * 512]);
            gll16(Yb + (long)(ntb * 32 + row) * 512 + k0 + srcg * 8, &Blds[w * 512]);
        }
        __syncthreads();
#pragma unroll
        for (int kt = 0; kt < 2; kt++) {
            int g2 = kt * 4 + q;
            int arow = wr * 16 + r;
            bf16x8 a = *(bf16x8*)&Alds[arow * 64 + ((g2 ^ (arow & 7)) << 3)];
            int brow = wc * 16 + r;
            bf16x8 b = *(bf16x8*)&Blds[brow * 64 + ((g2 ^ (brow & 7)) << 3)];
            acc = MFMA16(a, b, acc);
        }
        __syncthreads();
    }

    {
        int m = mb * 32 + wr * 16 + q * 4;
        int n = ntb * 32 + wc * 16 + r;
#pragma unroll
        for (int v = 0; v < 4; v++)
            E2s[(long)(1 + g) * 32768 + (long)(m + v) * 512 + n] = f2bf(acc[v]);
    }
}

// ---------------------------------------------------------------------------
// s1x: S1[c'] = E2slab[g].A^{8j} + [j==0 && g>=1] E2slab[g-1].A^64
//             + sum_{t<j} E1[8g+t].A^{8(j-1-t)}      (c' = 8g+j)
// c' in 0..128 (c'=128: g=16,j=0 -> E2[15] + E2[14].A^64).
// Writes: Z state cols (c'<=127, bf16) AND dout[t=8c'-1] (c'>=1, fp32).
// grid 516.  j-BALANCED mapping for c'<128.
// ---------------------------------------------------------------------------
__global__ __launch_bounds__(256, 4) void s1x(float* __restrict__ dout,
                                              char* __restrict__ ws) {
    __shared__ ushort_t Alds[64 * 64];
    __shared__ ushort_t Blds[128 * 64];
    const ushort_t* At  = (const ushort_t*)(ws + OFF_AT);
    const ushort_t* E1s = (const ushort_t*)(ws + OFF_E1S);
    const ushort_t* E2s = (const ushort_t*)(ws + OFF_E2S);
    ushort_t* Z = (ushort_t*)(ws + OFF_Z);

    int bx = blockIdx.x;
    int t0 = bx >> 2, nt = bx & 3;
    int g, j;
    if (t0 == 128) { g = 16; j = 0; }
    else {
        g = t0 >> 3;
        int jj = t0 & 7;
        j = (g >= 8) ? (7 - jj) : jj;    // balance heavy/light across CUs
    }
    int c = g * 8 + j;
    int extra = (j == 0 && g >= 1) ? 1 : 0;
    int nterms = 1 + extra + j;
    int S = nterms * 8;
    int tid = threadIdx.x, w = tid >> 6, lane = tid & 63, q = lane >> 4, r = lane & 15;
    int wr = w >> 1, wc = w & 1;
    int l8 = lane >> 3, srcg = (lane & 7) ^ l8;

    auto xptr = [&](int t) -> const ushort_t* {
        if (t == 0) return E2s + (long)g * 32768;
        if (extra && t == 1) return E2s + (long)(g - 1) * 32768;
        return E1s + (long)(8 * g + t - 1 - extra) * 32768;
    };
    auto yptr = [&](int t) -> const ushort_t* {
        int p = (t == 0) ? 8 * j : ((extra && t == 1) ? 64 : 8 * (j - t + extra));
        return At + (long)slot_of(p) * 262144;
    };

    f32x4 acc[2][4];
#pragma unroll
    for (int a1 = 0; a1 < 2; a1++)
#pragma unroll
        for (int b1 = 0; b1 < 4; b1++) acc[a1][b1] = (f32x4){0.f, 0.f, 0.f, 0.f};

    for (int s = 0; s < S; s++) {
        int t = s >> 3, k0 = (s & 7) * 64;
        const ushort_t* Xp = xptr(t);
        const ushort_t* Yb = yptr(t);
#pragma unroll
        for (int i = 0; i < 2; i++) {
            int row = i * 32 + w * 8 + l8;
            gll16(Xp + (long)row * 512 + k0 + srcg * 8, &Alds[i * 2048 + w * 512]);
        }
#pragma unroll
        for (int i = 0; i < 4; i++) {
            int row = i * 32 + w * 8 + l8;
            gll16(Yb + (long)(nt * 128 + row) * 512 + k0 + srcg * 8, &Blds[i * 2048 + w * 512]);
        }
        __syncthreads();
#pragma unroll
        for (int kt = 0; kt < 2; kt++) {
            int g2 = kt * 4 + q;
            bf16x8 a[2], b[4];
#pragma unroll
            for (int mi = 0; mi < 2; mi++) {
                int row = wr * 32 + mi * 16 + r;
                a[mi] = *(bf16x8*)&Alds[row * 64 + ((g2 ^ (row & 7)) << 3)];
            }
#pragma unroll
            for (int nj = 0; nj < 4; nj++) {
                int row = wc * 64 + nj * 16 + r;
                b[nj] = *(bf16x8*)&Blds[row * 64 + ((g2 ^ (row & 7)) << 3)];
            }
#pragma unroll
            for (int mi = 0; mi < 2; mi++)
#pragma unroll
                for (int nj = 0; nj < 4; nj++)
                    acc[mi][nj] = MFMA16(a[mi], b[nj], acc[mi][nj]);
        }
        __syncthreads();
    }

#pragma unroll
    for (int mi = 0; mi < 2; mi++)
#pragma unroll
        for (int nj = 0; nj < 4; nj++) {
            int m = wr * 32 + mi * 16 + q * 4;
            int n = nt * 128 + wc * 64 + nj * 16 + r;
#pragma unroll
            for (int v = 0; v < 4; v++) {
                float val = acc[mi][nj][v];
                int row = m + v;
                if (c < 128)
                    Z[(long)(c * 64 + row) * 1536 + n] = f2bf(val);
                if (c >= 1)
                    dout[(long)row * 524288 + (long)(8 * c - 1) * 512 + n] = val;
            }
        }
}

// ---------------------------------------------------------------------------
// outg: out[t=8c+k] for k=0..3.  k=3 blocks also write M[c]=x_{8c+4} (bf16)
// into the E1S region (dead after s1x).
// grid 1024: nt = bx>>8, rem = bx&255, k = 3-(rem>>6) [heavy first], mt = rem&63.
// ---------------------------------------------------------------------------
__global__ __launch_bounds__(256, 4) void outg(float* __restrict__ dout,
                                               char* __restrict__ ws) {
    __shared__ ushort_t Alds[128 * 64];
    __shared__ ushort_t Blds[128 * 64];
    const ushort_t* Z  = (const ushort_t*)(ws + OFF_Z);
    const ushort_t* At = (const ushort_t*)(ws + OFF_AT);
    const ushort_t* Wt = (const ushort_t*)(ws + OFF_WT);
    ushort_t* M = (ushort_t*)(ws + OFF_E1S);   // mid-state, reuses E1 slab

    int bx = blockIdx.x;
    int nt = bx >> 8;
    int rem = bx & 255;
    int k = 3 - (rem >> 6);      // heavy k first -> light tail
    int mt = rem & 63;
    int tid = threadIdx.x, w = tid >> 6, lane = tid & 63, q = lane >> 4, r = lane & 15;
    int wr = w >> 1, wc = w & 1;
    int l8 = lane >> 3, srcg = (lane & 7) ^ l8;

    const ushort_t* Xb = Z + (long)mt * 128 * 1536;
    const ushort_t* Ya = At + (long)slot_of(k + 1) * 262144;
    int Ks = 8 + 2 * (k + 1);

    f32x4 acc[4][4];
#pragma unroll
    for (int a1 = 0; a1 < 4; a1++)
#pragma unroll
        for (int b1 = 0; b1 < 4; b1++) acc[a1][b1] = (f32x4){0.f, 0.f, 0.f, 0.f};

    for (int s = 0; s < Ks; s++) {
        int k0 = s * 64;
#pragma unroll
        for (int i = 0; i < 4; i++) {
            int row = i * 32 + w * 8 + l8;
            gll16(Xb + (long)row * 1536 + k0 + srcg * 8, &Alds[i * 2048 + w * 512]);
        }
        if (k0 < 512) {
#pragma unroll
            for (int i = 0; i < 4; i++) {
                int row = i * 32 + w * 8 + l8;
                gll16(Ya + (long)(nt * 128 + row) * 512 + k0 + srcg * 8, &Blds[i * 2048 + w * 512]);
            }
        } else {
            int uc = k0 - 512;
            const ushort_t* Yb = Wt + (long)(k - (uc >> 7)) * 65536 + (uc & 127);
#pragma unroll
            for (int i = 0; i < 4; i++) {
                int row = i * 32 + w * 8 + l8;
                gll16(Yb + (long)(nt * 128 + row) * 128 + srcg * 8, &Blds[i * 2048 + w * 512]);
            }
        }
        __syncthreads();
#pragma unroll
        for (int kt = 0; kt < 2; kt++) {
            int g2 = kt * 4 + q;
            bf16x8 a[4], b[4];
#pragma unroll
            for (int mi = 0; mi < 4; mi++) {
                int row = wr * 64 + mi * 16 + r;
                a[mi] = *(bf16x8*)&Alds[row * 64 + ((g2 ^ (row & 7)) << 3)];
            }
#pragma unroll
            for (int nj = 0; nj < 4; nj++) {
                int row = wc * 64 + nj * 16 + r;
                b[nj] = *(bf16x8*)&Blds[row * 64 + ((g2 ^ (row & 7)) << 3)];
            }
#pragma unroll
            for (int mi = 0; mi < 4; mi++)
#pragma unroll
                for (int nj = 0; nj < 4; nj++)
                    acc[mi][nj] = MFMA16(a[mi], b[nj], acc[mi][nj]);
        }
        __syncthreads();
    }

#pragma unroll
    for (int mi = 0; mi < 4; mi++) {
        int m = mt * 128 + wr * 64 + mi * 16 + q * 4;
#pragma unroll
        for (int nj = 0; nj < 4; nj++) {
            int n = nt * 128 + wc * 64 + nj * 16 + r;
#pragma unroll
            for (int v = 0; v < 4; v++) {
                int mm = m + v;
                float val = acc[mi][nj][v];
                dout[(long)(mm & 63) * 524288 + (long)(((mm >> 6) << 3) + k) * 512 + n] = val;
                if (k == 3)
                    M[(long)mm * 512 + n] = f2bf(val);
            }
        }
    }
}

// ---------------------------------------------------------------------------
// outg2: out[t=8c+4+kp] for kp=0..2 (actual k=kp+4):
//   x = M[c].A^{kp+1} + sum_{j'=0..kp} u_{4+j'}.(B.A^{kp-j'})
// grid 768: nt = bx/192, rem = bx%192, kp = 2-(rem>>6) [heavy first], mt = rem&63.
// ---------------------------------------------------------------------------
__global__ __launch_bounds__(256, 4) void outg2(float* __restrict__ dout,
                                                char* __restrict__ ws) {
    __shared__ ushort_t Alds[128 * 64];
    __shared__ ushort_t Blds[128 * 64];
    const ushort_t* Z  = (const ushort_t*)(ws + OFF_Z);
    const ushort_t* At = (const ushort_t*)(ws + OFF_AT);
    const ushort_t* Wt = (const ushort_t*)(ws + OFF_WT);
    const ushort_t* M  = (const ushort_t*)(ws + OFF_E1S);

    int bx = blockIdx.x;
    int nt = bx / 192;
    int rem = bx - nt * 192;
    int kp = 2 - (rem >> 6);     // heavy first
    int mt = rem & 63;
    int tid = threadIdx.x, w = tid >> 6, lane = tid & 63, q = lane >> 4, r = lane & 15;
    int wr = w >> 1, wc = w & 1;
    int l8 = lane >> 3, srcg = (lane & 7) ^ l8;

    const ushort_t* Xm = M + (long)mt * 128 * 512;            // state part
    const ushort_t* Xu = Z + (long)mt * 128 * 1536 + 1024;    // u_4.. cols
    const ushort_t* Ya = At + (long)slot_of(kp + 1) * 262144;
    int Ks = 8 + 2 * (kp + 1);

    f32x4 acc[4][4];
#pragma unroll
    for (int a1 = 0; a1 < 4; a1++)
#pragma unroll
        for (int b1 = 0; b1 < 4; b1++) acc[a1][b1] = (f32x4){0.f, 0.f, 0.f, 0.f};

    for (int s = 0; s < Ks; s++) {
        int k0 = s * 64;
        if (k0 < 512) {
#pragma unroll
            for (int i = 0; i < 4; i++) {
                int row = i * 32 + w * 8 + l8;
                gll16(Xm + (long)row * 512 + k0 + srcg * 8, &Alds[i * 2048 + w * 512]);
            }
#pragma unroll
            for (int i = 0; i < 4; i++) {
                int row = i * 32 + w * 8 + l8;
                gll16(Ya + (long)(nt * 128 + row) * 512 + k0 + srcg * 8, &Blds[i * 2048 + w * 512]);
            }
        } else {
            int uc = k0 - 512;
#pragma unroll
            for (int i = 0; i < 4; i++) {
                int row = i * 32 + w * 8 + l8;
                gll16(Xu + (long)row * 1536 + uc + srcg * 8, &Alds[i * 2048 + w * 512]);
            }
            const ushort_t* Yb = Wt + (long)(kp - (uc >> 7)) * 65536 + (uc & 127);
#pragma unroll
            for (int i = 0; i < 4; i++) {
                int row = i * 32 + w * 8 + l8;
                gll16(Yb + (long)(nt * 128 + row) * 128 + srcg * 8, &Blds[i * 2048 + w * 512]);
            }
        }
        __syncthreads();
#pragma unroll
        for (int kt = 0; kt < 2; kt++) {
            int g2 = kt * 4 + q;
            bf16x8 a[4], b[4];
#pragma unroll
            for (int mi = 0; mi < 4; mi++) {
                int row = wr * 64 + mi * 16 + r;
                a[mi] = *(bf16x8*)&Alds[row * 64 + ((g2 ^ (row & 7)) << 3)];
            }
#pragma unroll
            for (int nj = 0; nj < 4; nj++) {
                int row = wc * 64 + nj * 16 + r;
                b[nj] = *(bf16x8*)&Blds[row * 64 + ((g2 ^ (row & 7)) << 3)];
            }
#pragma unroll
            for (int mi = 0; mi < 4; mi++)
#pragma unroll
                for (int nj = 0; nj < 4; nj++)
                    acc[mi][nj] = MFMA16(a[mi], b[nj], acc[mi][nj]);
        }
        __syncthreads();
    }

#pragma unroll
    for (int mi = 0; mi < 4; mi++) {
        int m = mt * 128 + wr * 64 + mi * 16 + q * 4;
#pragma unroll
        for (int nj = 0; nj < 4; nj++) {
            int n = nt * 128 + wc * 64 + nj * 16 + r;
#pragma unroll
            for (int v = 0; v < 4; v++) {
                int mm = m + v;
                dout[(long)(mm & 63) * 524288 + (long)(((mm >> 6) << 3) + 4 + kp) * 512 + n] = acc[mi][nj][v];
            }
        }
    }
}

// ---------------------------------------------------------------------------
extern "C" void kernel_launch(void* const* d_in, const int* in_sizes, int n_in,
                              void* d_out, int out_size, void* d_ws, size_t ws_size,
                              hipStream_t stream) {
    const float* x0 = (const float*)d_in[0];
    const float* us = (const float*)d_in[1];
    const float* A  = (const float*)d_in[2];
    const float* B  = (const float*)d_in[3];
    float* dout = (float*)d_out;
    char* ws = (char*)d_ws;

    prep_kernel<<<2048, 256, 0, stream>>>(A, ws);

    // power ladder, grid 256 each stage:
    //   stage 0 riders: B/x0/identity (umode 1)
    //   stage 3 carries wk (blocks 64..127); u-pack rides stages 1,3,4,5
    const int stdual[6]  = {1, 1, 1, 1, 1, 0};
    const int stwk[6]    = {0, 0, 0, 64, 0, 0};
    const int stub[6]    = {64, 128, 0, 128, 128, 128};    // ubase (0 = none)
    const int stum[6]    = {1, 0, 0, 0, 0, 0};             // umode
    const int stus[6]    = {0, 0, 0, 262144, 524288, 786432};
    const int stue[6]    = {0, 262144, 0, 524288, 786432, 1048576};
    const int stpw[6]    = {64, 128, 256, 64, 128, 128};
    const int std_[6][4] = {{2,0,0,0},{3,4,0,0},{5,6,7,8},{16,0,0,0},{24,32,0,0},{40,48,56,64}};
    const int stm[6][4]  = {{1,0,0,0},{2,2,0,0},{4,4,4,4},{8,0,0,0},{16,16,0,0},{32,32,32,32}};
    const int sti[6][4]  = {{1,0,0,0},{1,2,0,0},{1,2,3,4},{8,0,0,0},{8,16,0,0},{8,16,24,32}};
    for (int s = 0; s < 6; s++) {
        int4 dd = {std_[s][0], std_[s][1], std_[s][2], std_[s][3]};
        int4 mm = {stm[s][0], stm[s][1], stm[s][2], stm[s][3]};
        int4 ii = {sti[s][0], sti[s][1], sti[s][2], sti[s][3]};
        int blocks = (stub[s] > 0) ? 256 : stpw[s] + stwk[s];
        pow_stage<<<blocks, 256, 0, stream>>>(ws, us, x0, B, dd, mm, ii,
                                              stdual[s], stwk[s], stub[s],
                                              stum[s], stus[s], stue[s]);
    }

    e1g<<<512, 256, 0, stream>>>(ws);           // E1 -> E1slab
    e2g<<<512, 256, 0, stream>>>(ws);           // E2 -> E2slab[1+g]
    s1x<<<516, 256, 0, stream>>>(dout, ws);     // S1 -> Z state + dout k=7 slices
    outg<<<1024, 256, 0, stream>>>(dout, ws);   // k=0..3 + mid-state M
    outg2<<<768, 256, 0, stream>>>(dout, ws);   // k=4..6 from M
}